// Round 7
// baseline (103622.253 us; speedup 1.0000x reference)
//
#include <hip/hip_runtime.h>
#include <math.h>
#include <stddef.h>

// ---------------------------------------------------------------------------
// ATT_SYN: bi-LSTM encoder + synopsis attention + 2nd bi-LSTM + tag head.
// B=8 T=512 S=32 J=64 D=400 R=256 MDU=100 TAGS=7
// Recurrence: 2-WG groups, weights resident in VGPRs/AGPRs (128/lane).
// KEY (r6 lesson): agent-scope RMWs execute in the issuing XCD's L2 — only
// coherent between WGs on the SAME XCD. Grid maps partner pairs to linear IDs
// differing by 8 (same XCD under %8 round-robin); an XCC_ID handshake verifies
// at runtime and falls back to fenced (release/acquire) sync if split.
// ---------------------------------------------------------------------------

#define BB 8
#define TT 512
#define SS 32
#define JJ 64
#define DD 400
#define RR 256
#define G4 1024
#define H2 512
#define MDU_ 100
#define TAGS_ 7
#define BT (BB*TT)
#define NSEQ (BB*SS)
#define SCH 64
#define MB1 (1024*1024)

typedef __attribute__((ext_vector_type(8))) short short8;
typedef __attribute__((ext_vector_type(4))) float floatx4;
typedef __attribute__((ext_vector_type(2))) float floatx2;
typedef __attribute__((ext_vector_type(4))) unsigned int u32x4;
typedef unsigned short u16;
typedef unsigned int u32;

__device__ __forceinline__ float us2f(u16 u) {
    unsigned int v = ((unsigned int)u) << 16;
    return __builtin_bit_cast(float, v);
}
__device__ __forceinline__ u16 f2us(float f) {
    unsigned int v = __builtin_bit_cast(unsigned int, f);
    v += 0x7FFFu + ((v >> 16) & 1u);
    return (u16)(v >> 16);
}
__device__ __forceinline__ float ldin(const void* p, long i, int bf) {
    return bf ? us2f(((const u16*)p)[i]) : ((const float*)p)[i];
}
__device__ __forceinline__ float sigm(float x) { return 1.0f / (1.0f + expf(-x)); }
__device__ __forceinline__ float fsig(float x) {
    return __builtin_amdgcn_rcpf(1.f + __expf(-x));
}
__device__ __forceinline__ float ftanh(float x) {
    x = fminf(10.f, fmaxf(-10.f, x));
    float t = __expf(2.f * x);
    return (t - 1.f) * __builtin_amdgcn_rcpf(t + 1.f);
}

// ---- dtype probe ----
__global__ void detect_k(const void* x, int* flag) {
    __shared__ int cnt;
    if (threadIdx.x == 0) cnt = 0;
    __syncthreads();
    u16 lo = ((const u16*)x)[threadIdx.x * 2];
    int e = (lo >> 7) & 0xFF;
    if (e >= 118 && e <= 131) atomicAdd(&cnt, 1);
    __syncthreads();
    if (threadIdx.x == 0) *flag = (cnt > 128) ? 1 : 0;
}
__global__ void castbf_k(const void* src, long off, u16* dst, long n, const int* flag) {
    long i = (long)blockIdx.x * 256 + threadIdx.x;
    if (i < n) dst[i] = (*flag) ? ((const u16*)src)[off + i] : f2us(((const float*)src)[off + i]);
}
__global__ void castf_k(const void* src, float* dst, long n, const int* flag) {
    long i = (long)blockIdx.x * 256 + threadIdx.x;
    if (i < n) dst[i] = ldin(src, i, *flag);
}
__global__ void zero_k(u32* p, long n) {
    long i = (long)blockIdx.x * 256 + threadIdx.x;
    if (i < n) p[i] = 0u;
}
__global__ void bias_sum_k(const void* bih, const void* bhh, float* out, const int* flag) {
    int i = blockIdx.x * 256 + threadIdx.x;
    if (i < G4) out[i] = ldin(bih, i, *flag) + ldin(bhh, i, *flag);
}
__global__ void wsum_k(const void* a, const void* b, u16* o, const int* flag) {
    int i = blockIdx.x * 256 + threadIdx.x;
    if (i < H2 * H2) o[i] = f2us(ldin(a, i, *flag) + ldin(b, i, *flag));
}
// Whh [1024,256] -> pre-swizzled MFMA B-frags for 2-WG (p) x 8-wave (w):
// n_g = gt*256 + p*128 + hh*64 + t4*16 + (ln&15), gt=w>>1, hh=w&1
__global__ void whh_frag_k(const void* Whh, u16* WF, const int* flag) {
    int i = blockIdx.x * 256 + threadIdx.x;
    if (i >= 262144) return;
    int j  = i & 7;
    int ln = (i >> 3) & 63;
    int c  = (i >> 9) & 7;
    int t4 = (i >> 12) & 3;
    int w  = (i >> 14) & 7;
    int p  = (i >> 17) & 1;
    int gt = w >> 1, hh = w & 1;
    int n_g = gt * 256 + p * 128 + hh * 64 + t4 * 16 + (ln & 15);
    int k   = c * 32 + (ln >> 4) * 8 + j;
    WF[i] = f2us(ldin(Whh, (long)n_g * 256 + k, *flag));
}

// ---------------------------------------------------------------------------
// GEMM: C[M,N] = A[M,K] @ W[N,K]^T (+bias). A/W internal bf16 or RAW (per flag).
// ---------------------------------------------------------------------------
#define BM 128
#define BN 128
#define BK 32
#define LDT 40

__global__ __launch_bounds__(256)
void gemm_bt(const void* __restrict__ A, long aOff, int lda,
             const void* __restrict__ W, int ldw,
             void* __restrict__ C, int ldc,
             const float* __restrict__ bias,
             int M, int N, int K, int outBf16,
             int aRaw, int wRaw, const int* __restrict__ flagp)
{
    __shared__ alignas(16) short As[BM * LDT];
    __shared__ alignas(16) short Bs[BN * LDT];
    const int bf = flagp ? *flagp : 1;
    const int af32 = aRaw && !bf;
    const int wf32 = wRaw && !bf;
    const u16* A16 = (const u16*)A;
    const float* AF = (const float*)A;
    const u16* W16 = (const u16*)W;
    const float* WFp = (const float*)W;

    const int tid  = threadIdx.x;
    const int m0   = blockIdx.y * BM;
    const int n0   = blockIdx.x * BN;
    const int lane = tid & 63;
    const int wave = tid >> 6;
    const int wm   = wave >> 1, wn = wave & 1;
    const int quad = lane >> 4, mrow = lane & 15;

    floatx4 acc[4][4];
#pragma unroll
    for (int i = 0; i < 4; ++i)
#pragma unroll
        for (int j = 0; j < 4; ++j) { floatx4 z4 = {0.f,0.f,0.f,0.f}; acc[i][j] = z4; }

    for (int k0 = 0; k0 < K; k0 += BK) {
#pragma unroll
        for (int cc = 0; cc < 2; ++cc) {
            int c   = tid + cc * 256;
            int row = c >> 2;
            int kc  = (c & 3) << 3;
            int gk  = k0 + kc;
            {   // A tile
                int gr = m0 + row;
                short8 v;
                size_t idx = (size_t)aOff + (size_t)gr * lda + gk;
                if (gr < M && gk + 8 <= K) {
                    if (af32) {
                        floatx4 f0 = *(const floatx4*)(AF + idx);
                        floatx4 f1 = *(const floatx4*)(AF + idx + 4);
#pragma unroll
                        for (int e = 0; e < 4; ++e) { v[e] = (short)f2us(f0[e]); v[4+e] = (short)f2us(f1[e]); }
                    } else {
                        v = *(const short8*)(A16 + idx);
                    }
                } else {
#pragma unroll
                    for (int e = 0; e < 8; ++e) {
                        u16 x = 0;
                        if (gr < M && (gk + e) < K)
                            x = af32 ? f2us(AF[idx + e]) : A16[idx + e];
                        v[e] = (short)x;
                    }
                }
                *(short8*)&As[row * LDT + kc] = v;
            }
            {   // W tile
                int gn = n0 + row;
                short8 v;
                size_t idx = (size_t)gn * ldw + gk;
                if (gn < N && gk + 8 <= K) {
                    if (wf32) {
                        floatx4 f0 = *(const floatx4*)(WFp + idx);
                        floatx4 f1 = *(const floatx4*)(WFp + idx + 4);
#pragma unroll
                        for (int e = 0; e < 4; ++e) { v[e] = (short)f2us(f0[e]); v[4+e] = (short)f2us(f1[e]); }
                    } else {
                        v = *(const short8*)(W16 + idx);
                    }
                } else {
#pragma unroll
                    for (int e = 0; e < 8; ++e) {
                        u16 x = 0;
                        if (gn < N && (gk + e) < K)
                            x = wf32 ? f2us(WFp[idx + e]) : W16[idx + e];
                        v[e] = (short)x;
                    }
                }
                *(short8*)&Bs[row * LDT + kc] = v;
            }
        }
        __syncthreads();

        short8 af[4], bfr[4];
#pragma unroll
        for (int i = 0; i < 4; ++i)
            af[i] = *(const short8*)&As[(wm * 64 + i * 16 + mrow) * LDT + quad * 8];
#pragma unroll
        for (int j = 0; j < 4; ++j)
            bfr[j] = *(const short8*)&Bs[(wn * 64 + j * 16 + mrow) * LDT + quad * 8];
#pragma unroll
        for (int i = 0; i < 4; ++i)
#pragma unroll
            for (int j = 0; j < 4; ++j)
                acc[i][j] = __builtin_amdgcn_mfma_f32_16x16x32_bf16(af[i], bfr[j], acc[i][j], 0, 0, 0);
        __syncthreads();
    }

#pragma unroll
    for (int i = 0; i < 4; ++i)
#pragma unroll
        for (int j = 0; j < 4; ++j)
#pragma unroll
            for (int r = 0; r < 4; ++r) {
                int row = m0 + wm * 64 + i * 16 + quad * 4 + r;
                int col = n0 + wn * 64 + j * 16 + mrow;
                if (row < M && col < N) {
                    float v = acc[i][j][r];
                    if (bias) v += bias[col];
                    if (outBf16) ((u16*)C)[(size_t)row * ldc + col] = f2us(v);
                    else         ((float*)C)[(size_t)row * ldc + col] = v;
                }
            }
}

// ---------------------------------------------------------------------------
// Cooperative LSTM v4: grid (16, 2, nb); slot=x&7, p=x>>3; active iff
// slot==(dir*4+bat)&7 -> partner linear IDs differ by 8 => same XCD (%8 rr).
// XCC_ID handshake picks: fast path (relaxed RMW, same-L2 coherent) or
// fenced fallback (release/acquire, round-4 semantics) if pair is split.
// Flag published only after __syncthreads drains ALL waves' h-RMWs.
// ---------------------------------------------------------------------------
__global__ __launch_bounds__(512, 2)
void lstm_coop2(const u16* __restrict__ xWf, const u16* __restrict__ xWb,
                const u16* __restrict__ WFf, const u16* __restrict__ WFb,
                int L,
                u16* __restrict__ hOut, int hStride,
                u16* __restrict__ cOut, int cStride,
                const int* __restrict__ lenp,
                int writeAtSource, int lastOnly, int seqBase,
                u32* __restrict__ hx32, u32* __restrict__ flags,
                u32* __restrict__ xcdTab, int grpBase)
{
    const int slot = blockIdx.x & 7;
    const int p    = blockIdx.x >> 3;
    const int dir  = blockIdx.y;
    const int bat  = blockIdx.z;
    const int nb   = gridDim.z;
    if (slot != ((dir * 4 + bat) & 7)) return;   // inactive placement block

    const int tid = threadIdx.x;
    const int w   = tid >> 6;
    const int ln  = tid & 63;
    const int q   = ln >> 4, m = ln & 15;
    const u16* xW = dir ? xWb : xWf;
    const u16* WF = dir ? WFb : WFf;
    const int grp = grpBase + dir * nb + bat;
    u32* hx       = hx32 + (size_t)grp * 2048;     // [2][8 seq][128 u32]
    u32* flagOwn  = flags + (size_t)grp * 32 + p * 16;
    u32* flagOth  = flags + (size_t)grp * 32 + (1 - p) * 16;

    __shared__ float g_s[8 * 520];      // [seq][col 512 pad 520]
    __shared__ u32 hls[8][68];          // own h slice
    __shared__ int fastS;

    // ---- one-time XCD handshake (SEQ_CST = fully fenced, cross-XCD safe) ----
    if (tid == 0) {
        u32 my = (u32)(__builtin_amdgcn_s_getreg((3 << 11) | 20) & 0xF) + 1u;  // HW_REG_XCC_ID
        __hip_atomic_exchange(xcdTab + grp * 2 + p, my,
                              __ATOMIC_SEQ_CST, __HIP_MEMORY_SCOPE_AGENT);
        u32 o = 0; int it = 0;
        do {
            o = __hip_atomic_fetch_add(xcdTab + grp * 2 + (1 - p), 0u,
                                       __ATOMIC_SEQ_CST, __HIP_MEMORY_SCOPE_AGENT);
        } while (o == 0u && ++it < (1 << 20));
        fastS = (o == my) ? 1 : 0;
    }
    __syncthreads();
    const int fastSync = fastS;

    // resident weights: 4 N-tiles x 8 K-chunks (128 VGPR/AGPR per lane)
    short8 bw[4][8];
    {
        const u16* wb = WF + (size_t)(p * 8 + w) * 32 * 512 + ln * 8;
#pragma unroll
        for (int t4 = 0; t4 < 4; ++t4)
#pragma unroll
            for (int c = 0; c < 8; ++c)
                bw[t4][c] = *(const short8*)(wb + (size_t)(t4 * 8 + c) * 512);
    }

    const int seqU = tid >> 6;             // wave == seq for update phase
    const int jh   = tid & 63;             // unit pair index (j0 = 2*jh)
    float c0 = 0.f, c1 = 0.f;

    // prefetch xW gates for t=0
    u32 xw0, xw1, xw2, xw3;
    {
        int tt0 = dir ? (L - 1) : 0;
        const u16* xr = xW + ((size_t)(bat * 8 + seqU) * L + tt0) * G4 + p * 128 + jh * 2;
        xw0 = *(const u32*)(xr);
        xw1 = *(const u32*)(xr + 256);
        xw2 = *(const u32*)(xr + 512);
        xw3 = *(const u32*)(xr + 768);
    }

    for (int t = 0; t < L; ++t) {
        const int tt = dir ? (L - 1 - t) : t;
        // ---- A fragments ----
        short8 a[8];
        {
            short8 z = {0,0,0,0,0,0,0,0};
#pragma unroll
            for (int c = 0; c < 8; ++c) a[c] = z;
        }
        if (t > 0 && m < 8) {
            const int bsel = (t - 1) & 1;
            // partner slice: 16 relaxed RMW reads (same-XCD L2 -> coherent+fast)
            u32* hp = hx + bsel * 1024 + m * 128 + (1 - p) * 64;
#pragma unroll
            for (int co = 0; co < 4; ++co) {
                u32x4 vv;
#pragma unroll
                for (int e = 0; e < 4; ++e)
                    vv[e] = __hip_atomic_fetch_add(hp + co * 16 + q * 4 + e, 0u,
                                                   __ATOMIC_RELAXED, __HIP_MEMORY_SCOPE_AGENT);
                a[(1 - p) * 4 + co] = __builtin_bit_cast(short8, vv);
            }
            // own slice from LDS
#pragma unroll
            for (int co = 0; co < 4; ++co) {
                u32x4 vv = *(const u32x4*)&hls[m][co * 16 + q * 4];
                a[p * 4 + co] = __builtin_bit_cast(short8, vv);
            }
        }
        floatx4 acc[4];
#pragma unroll
        for (int t4 = 0; t4 < 4; ++t4) { floatx4 z4 = {0.f,0.f,0.f,0.f}; acc[t4] = z4; }
#pragma unroll
        for (int t4 = 0; t4 < 4; ++t4)
#pragma unroll
            for (int c = 0; c < 8; ++c)
                acc[t4] = __builtin_amdgcn_mfma_f32_16x16x32_bf16(a[c], bw[t4][c], acc[t4], 0, 0, 0);
        if (q < 2) {
#pragma unroll
            for (int t4 = 0; t4 < 4; ++t4)
#pragma unroll
                for (int r = 0; r < 4; ++r)
                    g_s[(q * 4 + r) * 520 + w * 64 + t4 * 16 + m] = acc[t4][r];
        }
        __syncthreads();
        // ---- gate fuse + state update (thread -> seqU, units 2jh, 2jh+1) ----
        float hn0, hn1, cn0, cn1;
        {
            floatx2 gi = *(const floatx2*)&g_s[seqU * 520 + 0 * 128 + jh * 2];
            floatx2 gf = *(const floatx2*)&g_s[seqU * 520 + 1 * 128 + jh * 2];
            floatx2 gg = *(const floatx2*)&g_s[seqU * 520 + 2 * 128 + jh * 2];
            floatx2 go = *(const floatx2*)&g_s[seqU * 520 + 3 * 128 + jh * 2];
            float i0 = gi[0] + us2f((u16)(xw0 & 0xFFFF)), i1 = gi[1] + us2f((u16)(xw0 >> 16));
            float f0 = gf[0] + us2f((u16)(xw1 & 0xFFFF)), f1 = gf[1] + us2f((u16)(xw1 >> 16));
            float g0 = gg[0] + us2f((u16)(xw2 & 0xFFFF)), g1 = gg[1] + us2f((u16)(xw2 >> 16));
            float o0 = go[0] + us2f((u16)(xw3 & 0xFFFF)), o1 = go[1] + us2f((u16)(xw3 >> 16));
            cn0 = fsig(f0) * c0 + fsig(i0) * ftanh(g0);
            cn1 = fsig(f1) * c1 + fsig(i1) * ftanh(g1);
            hn0 = fsig(o0) * ftanh(cn0);
            hn1 = fsig(o1) * ftanh(cn1);
            c0 = cn0; c1 = cn1;
            u32 hpack = (u32)f2us(hn0) | ((u32)f2us(hn1) << 16);
            hls[seqU][jh] = hpack;
            // publish own slice via RMW (executes at L2)
            __hip_atomic_exchange(hx + (t & 1) * 1024 + seqU * 128 + p * 64 + jh, hpack,
                                  __ATOMIC_RELAXED, __HIP_MEMORY_SCOPE_AGENT);
        }
        // prefetch next xW + deferred output stores
        if (t + 1 < L) {
            int tt2 = dir ? (L - 2 - t) : (t + 1);
            const u16* xr = xW + ((size_t)(bat * 8 + seqU) * L + tt2) * G4 + p * 128 + jh * 2;
            xw0 = *(const u32*)(xr);
            xw1 = *(const u32*)(xr + 256);
            xw2 = *(const u32*)(xr + 512);
            xw3 = *(const u32*)(xr + 768);
        }
        if (!lastOnly) {
            int wr = writeAtSource ? tt : t;
            float mk = (lenp && wr >= lenp[bat * 8 + seqU]) ? 0.f : 1.f;
            size_t ro = (size_t)(bat * 8 + seqU) * L + wr;
            u32 hp2 = (u32)f2us(hn0 * mk) | ((u32)f2us(hn1 * mk) << 16);
            *(u32*)(hOut + ro * hStride + dir * RR + p * 128 + jh * 2) = hp2;
            if (cOut) {
                u32 cp2 = (u32)f2us(cn0 * mk) | ((u32)f2us(cn1 * mk) << 16);
                *(u32*)(cOut + ro * cStride + dir * RR + p * 128 + jh * 2) = cp2;
            }
        } else if (t == L - 1) {
            size_t ro = (size_t)(seqBase + bat * 8 + seqU);
            u32 hp2 = (u32)f2us(hn0) | ((u32)f2us(hn1) << 16);
            *(u32*)(hOut + ro * hStride + dir * RR + p * 128 + jh * 2) = hp2;
        }
        // ---- drain ALL waves' h publishes, then flag + poll ----
        __syncthreads();   // compiler emits s_waitcnt vmcnt(0) before s_barrier
        if (tid == 0) {
            if (fastSync) {
                __hip_atomic_exchange(flagOwn, (u32)(t + 1),
                                      __ATOMIC_RELAXED, __HIP_MEMORY_SCOPE_AGENT);
                int g = 0;
                while (__hip_atomic_fetch_add(flagOth, 0u,
                           __ATOMIC_RELAXED, __HIP_MEMORY_SCOPE_AGENT) < (u32)(t + 1))
                    if (++g > (1 << 20)) break;
            } else {
                // fenced fallback: release writes back L2, acquire invalidates
                __hip_atomic_exchange(flagOwn, (u32)(t + 1),
                                      __ATOMIC_RELEASE, __HIP_MEMORY_SCOPE_AGENT);
                int g = 0;
                while (__hip_atomic_fetch_add(flagOth, 0u,
                           __ATOMIC_ACQUIRE, __HIP_MEMORY_SCOPE_AGENT) < (u32)(t + 1))
                    if (++g > (1 << 16)) break;
            }
        }
        __syncthreads();
    }
}

// ------------------------- small fused kernels -----------------------------
__global__ void hprev_k(const u16* __restrict__ G, u16* __restrict__ Hp) {
    int idx = blockIdx.x * 256 + threadIdx.x;
    if (idx < BT * H2) {
        int r = idx >> 9, d = idx & 511;
        int t = r & (TT - 1);
        Hp[idx] = (t == 0) ? (u16)0 : G[(size_t)(r - 1) * G4 + d];
    }
}
__global__ void s_k(const float* __restrict__ e, const u16* __restrict__ mB,
                    u16* __restrict__ sB) {
    int i = blockIdx.x * 256 + threadIdx.x;
    if (i < BT * H2) sB[i] = f2us(sigm(e[i]) * tanhf(us2f(mB[i])));
}
__global__ void z_k(const float* __restrict__ cWh, const float* __restrict__ cWu,
                    const float* __restrict__ Wv, float* __restrict__ z) {
    int idx = blockIdx.x * 256 + threadIdx.x;
    if (idx >= BT * SS) return;
    int r = idx >> 5, s = idx & 31;
    int b = r >> 9;
    const float* ph = cWh + (size_t)r * MDU_;
    const float* pu = cWu + (size_t)(b * SS + s) * MDU_;
    float acc = 0.f;
    for (int j = 0; j < MDU_; ++j) acc += tanhf(ph[j] + pu[j]) * Wv[j];
    z[idx] = acc;
}
__global__ void zhat_k(const float* __restrict__ sW, const float* __restrict__ cWh,
                       const float* __restrict__ Wv, float* __restrict__ zhat) {
    int r = blockIdx.x * 256 + threadIdx.x;
    if (r >= BT) return;
    float acc = 0.f;
    const float* ps = sW + (size_t)r * MDU_;
    const float* ph = cWh + (size_t)r * MDU_;
    for (int j = 0; j < MDU_; ++j) acc += tanhf(ps[j] + ph[j]) * Wv[j];
    zhat[r] = acc;
}
__global__ __launch_bounds__(64)
void attn_mix_k(const float* __restrict__ z, const float* __restrict__ zhat,
                const u16* __restrict__ U, const u16* __restrict__ sB,
                u16* __restrict__ G) {
    int r = blockIdx.x;
    int lane = threadIdx.x;
    int b = r >> 9;
    __shared__ float alpha[SS];
    float zv = (lane < SS) ? z[(size_t)r * SS + lane] : -1e30f;
    float mx = zv;
    for (int o = 32; o > 0; o >>= 1) mx = fmaxf(mx, __shfl_xor(mx, o));
    float ez = (lane < SS) ? expf(zv - mx) : 0.f;
    float s1 = ez;
    for (int o = 32; o > 0; o >>= 1) s1 += __shfl_xor(s1, o);
    float zh = zhat[r];
    float mx2 = fmaxf(mx, zh);
    float denom = s1 * expf(mx - mx2) + expf(zh - mx2);
    float beta = expf(zh - mx2) / denom;
    if (lane < SS) alpha[lane] = ez / s1;
    __syncthreads();
    for (int d = lane; d < H2; d += 64) {
        float cv = 0.f;
#pragma unroll 8
        for (int s2 = 0; s2 < SS; ++s2)
            cv += alpha[s2] * us2f(U[(size_t)(b * SS + s2) * H2 + d]);
        float sv = us2f(sB[(size_t)r * H2 + d]);
        G[(size_t)r * G4 + H2 + d] = f2us(beta * sv + (1.f - beta) * cv);
    }
}
__global__ __launch_bounds__(256)
void logit_k(const u16* __restrict__ G, const u16* __restrict__ Mb,
             const u16* __restrict__ Wout, const float* __restrict__ boutF,
             void* __restrict__ out, const int* __restrict__ flag) {
    int r = blockIdx.x * 4 + (threadIdx.x >> 6);
    if (r >= BT) return;
    int lane = threadIdx.x & 63;
    float acc[TAGS_] = {0, 0, 0, 0, 0, 0, 0};
    for (int k = lane; k < 1536; k += 64) {
        float v = (k < G4) ? us2f(G[(size_t)r * G4 + k]) : us2f(Mb[(size_t)r * H2 + (k - G4)]);
#pragma unroll
        for (int tg = 0; tg < TAGS_; ++tg) acc[tg] += v * us2f(Wout[tg * 1536 + k]);
    }
#pragma unroll
    for (int tg = 0; tg < TAGS_; ++tg) {
        float s = acc[tg];
        for (int o = 32; o > 0; o >>= 1) s += __shfl_xor(s, o);
        acc[tg] = s;
    }
    if (lane == 0) {
        int bf = *flag;
#pragma unroll
        for (int tg = 0; tg < TAGS_; ++tg) {
            float v = acc[tg] + boutF[tg];
            if (bf) ((u16*)out)[(size_t)r * TAGS_ + tg] = f2us(v);
            else    ((float*)out)[(size_t)r * TAGS_ + tg] = v;
        }
    }
}

// ---------------------------------------------------------------------------
extern "C" void kernel_launch(void* const* d_in, const int* in_sizes, int n_in,
                              void* d_out, int out_size, void* d_ws, size_t ws_size,
                              hipStream_t stream)
{
    const void* x_text = d_in[0];
    const void* x_syn  = d_in[1];
    const int* len_ctx = (const int*)d_in[3];
    const void *Wih[6], *Whh[6], *bih[6], *bhh[6];
    for (int l = 0; l < 6; ++l) {
        Wih[l] = d_in[5 + l * 4 + 0];
        Whh[l] = d_in[5 + l * 4 + 1];
        bih[l] = d_in[5 + l * 4 + 2];
        bhh[l] = d_in[5 + l * 4 + 3];
    }
    const void* W_cWh = d_in[29];
    const void* W_cWu = d_in[30];
    const void* W_v   = d_in[31];
    const void* W_sWh = d_in[32];
    const void* W_sWu = d_in[33];
    const void* W_Ws  = d_in[34];
    const void* W_out = d_in[35];
    const void* b_out = d_in[36];
    (void)in_sizes; (void)n_in; (void)out_size; (void)ws_size;

    char* ws = (char*)d_ws;
    size_t off = 0;
    auto alloc = [&](size_t bytes) -> void* {
        void* p = ws + off;
        off += (bytes + 255) & ~(size_t)255;
        return p;
    };
    int*   flagB  = (int*)alloc(256);
    float* bsum[6];
    for (int l = 0; l < 6; ++l) bsum[l] = (float*)alloc((size_t)G4 * 4);
    u16*   WsumB  = (u16*)alloc((size_t)H2 * H2 * 2);
    u16*   Ub     = (u16*)alloc((size_t)NSEQ * H2 * 2);
    u16*   Gb     = (u16*)alloc((size_t)BT * G4 * 2);
    u16*   mMb    = (u16*)alloc((size_t)BT * H2 * 2);
    float* cWhB   = (float*)alloc((size_t)BT * MDU_ * 4);
    float* cWuB   = (float*)alloc((size_t)NSEQ * MDU_ * 4);
    float* sWB    = (float*)alloc((size_t)BT * MDU_ * 4);
    float* zB     = (float*)alloc((size_t)BT * SS * 4);
    float* zhatB  = (float*)alloc((size_t)BT * 4);
    u16*   Wout16 = (u16*)alloc((size_t)TAGS_ * 1536 * 2);
    float* WvF    = (float*)alloc((size_t)MDU_ * 4);
    float* boutF  = (float*)alloc((size_t)TAGS_ * 4);
    u16*   WF[6];
    for (int l = 0; l < 6; ++l) WF[l] = (u16*)alloc((size_t)G4 * RR * 2);
    u32*   flagsB = (u32*)alloc((size_t)128 * 32 * 4);
    u32*   xcdTab = (u32*)alloc((size_t)256 * 4);
    u32*   hx32   = (u32*)alloc((size_t)128 * 2048 * 4);
    char*  BIG    = (char*)alloc((size_t)24 * MB1);

    u16*   bufA  = (u16*)BIG;                       // 8MB xW fwd
    u16*   bufB  = (u16*)(BIG + (size_t)8 * MB1);   // 8MB xW bwd
    u16*   HprevB = (u16*)BIG;                      // phase C overlays
    float* eBuf   = (float*)(BIG + (size_t)4 * MB1);
    u16*   sBuf   = (u16*)(BIG + (size_t)12 * MB1);
    u16*   mxWf  = (u16*)BIG;                       // phase D overlays
    u16*   mxWb  = (u16*)(BIG + (size_t)8 * MB1);

    auto cgrid = [](long n) { return dim3((unsigned)((n + 255) / 256)); };

    // ---- prep ----
    detect_k<<<dim3(1), dim3(256), 0, stream>>>(x_text, flagB);
    zero_k<<<cgrid(128 * 32 + 256), dim3(256), 0, stream>>>(flagsB, 128 * 32 + 256);
    castbf_k<<<cgrid(TAGS_ * 1536), dim3(256), 0, stream>>>(W_out, 0, Wout16, TAGS_ * 1536, flagB);
    castf_k<<<cgrid(MDU_), dim3(256), 0, stream>>>(W_v, WvF, MDU_, flagB);
    castf_k<<<cgrid(TAGS_), dim3(256), 0, stream>>>(b_out, boutF, TAGS_, flagB);
    for (int l = 0; l < 6; ++l) {
        bias_sum_k<<<dim3(4), dim3(256), 0, stream>>>(bih[l], bhh[l], bsum[l], flagB);
        whh_frag_k<<<dim3(1024), dim3(256), 0, stream>>>(Whh[l], WF[l], flagB);
    }
    wsum_k<<<cgrid(H2 * H2), dim3(256), 0, stream>>>(W_sWh, W_sWu, WsumB, flagB);

    // ---- phase A: synopsis (4 chunks of 64 seqs) -> U ----
    for (int c = 0; c < NSEQ / SCH; ++c) {
        long aOff = (long)c * SCH * JJ * DD;
        gemm_bt<<<dim3(8, (SCH * JJ) / BM), dim3(256), 0, stream>>>(
            x_syn, aOff, DD, Wih[2], DD, bufA, G4, bsum[2], SCH * JJ, G4, DD, 1, 1, 1, flagB);
        gemm_bt<<<dim3(8, (SCH * JJ) / BM), dim3(256), 0, stream>>>(
            x_syn, aOff, DD, Wih[3], DD, bufB, G4, bsum[3], SCH * JJ, G4, DD, 1, 1, 1, flagB);
        lstm_coop2<<<dim3(16, 2, 8), dim3(512), 0, stream>>>(
            bufA, bufB, WF[2], WF[3], JJ,
            Ub, H2, (u16*)nullptr, 0, (const int*)nullptr,
            0, 1, c * SCH, hx32, flagsB, xcdTab, 2 + c * 16);
    }

    // ---- phase B: context layer-1 -> H (Gb left), m (mMb) ----
    gemm_bt<<<dim3(8, 32), dim3(256), 0, stream>>>(
        x_text, 0, DD, Wih[0], DD, bufA, G4, bsum[0], BT, G4, DD, 1, 1, 1, flagB);
    gemm_bt<<<dim3(8, 32), dim3(256), 0, stream>>>(
        x_text, 0, DD, Wih[1], DD, bufB, G4, bsum[1], BT, G4, DD, 1, 1, 1, flagB);
    lstm_coop2<<<dim3(16, 2, 1), dim3(512), 0, stream>>>(
        bufA, bufB, WF[0], WF[1], TT,
        Gb, G4, mMb, H2, len_ctx, 0, 0, 0, hx32, flagsB, xcdTab, 0);

    // ---- phase C: attention ----
    gemm_bt<<<dim3(1, 32), dim3(256), 0, stream>>>(
        Gb, 0, G4, W_cWh, H2, cWhB, MDU_, nullptr, BT, MDU_, H2, 0, 0, 1, flagB);
    gemm_bt<<<dim3(1, 2), dim3(256), 0, stream>>>(
        Ub, 0, H2, W_cWu, H2, cWuB, MDU_, nullptr, NSEQ, MDU_, H2, 0, 0, 1, flagB);
    hprev_k<<<cgrid(BT * H2), dim3(256), 0, stream>>>(Gb, HprevB);
    gemm_bt<<<dim3(4, 32), dim3(256), 0, stream>>>(
        HprevB, 0, H2, WsumB, H2, eBuf, H2, nullptr, BT, H2, H2, 0, 0, 0, nullptr);
    s_k<<<cgrid(BT * H2), dim3(256), 0, stream>>>(eBuf, mMb, sBuf);
    gemm_bt<<<dim3(1, 32), dim3(256), 0, stream>>>(
        sBuf, 0, H2, W_Ws, H2, sWB, MDU_, nullptr, BT, MDU_, H2, 0, 0, 1, flagB);
    z_k<<<cgrid(BT * SS), dim3(256), 0, stream>>>(cWhB, cWuB, WvF, zB);
    zhat_k<<<cgrid(BT), dim3(256), 0, stream>>>(sWB, cWhB, WvF, zhatB);
    attn_mix_k<<<dim3(BT), dim3(64), 0, stream>>>(zB, zhatB, Ub, sBuf, Gb);

    // ---- phase D: layer-2 LSTMs over G -> M (into mMb) ----
    gemm_bt<<<dim3(8, 32), dim3(256), 0, stream>>>(
        Gb, 0, G4, Wih[4], G4, mxWf, G4, bsum[4], BT, G4, G4, 1, 0, 1, flagB);
    gemm_bt<<<dim3(8, 32), dim3(256), 0, stream>>>(
        Gb, 0, G4, Wih[5], G4, mxWb, G4, bsum[5], BT, G4, G4, 1, 0, 1, flagB);
    lstm_coop2<<<dim3(16, 2, 1), dim3(512), 0, stream>>>(
        mxWf, mxWb, WF[4], WF[5], TT,
        mMb, H2, (u16*)nullptr, 0, (const int*)nullptr, 1, 0, 0, hx32, flagsB, xcdTab, 66);

    // ---- output ----
    logit_k<<<dim3(BT / 4), dim3(256), 0, stream>>>(Gb, mMb, Wout16, boutF, d_out, flagB);
}

// Round 8
// 103174.036 us; speedup vs baseline: 1.0043x; 1.0043x over previous
//
#include <hip/hip_runtime.h>
#include <math.h>
#include <stddef.h>

// ---------------------------------------------------------------------------
// ATT_SYN: bi-LSTM encoder + synopsis attention + 2nd bi-LSTM + tag head.
// B=8 T=512 S=32 J=64 D=400 R=256 MDU=100 TAGS=7
// Recurrence: 2-WG groups, weights resident in VGPRs/AGPRs (128/lane).
// Sync (r4-r7 synthesis): WGs self-organize into pairs BY MEASURED XCD via a
// bulletin table. Same-XCD pair -> relaxed RMW sync in the shared L2 (fast).
// Cross-XCD pair -> r4's proven fenced path (threadfence + RELEASE fetch_add
// + ACQUIRE-load poll). Correctness never depends on dispatch placement.
// ---------------------------------------------------------------------------

#define BB 8
#define TT 512
#define SS 32
#define JJ 64
#define DD 400
#define RR 256
#define G4 1024
#define H2 512
#define MDU_ 100
#define TAGS_ 7
#define BT (BB*TT)
#define NSEQ (BB*SS)
#define SCH 64
#define MB1 (1024*1024)

typedef __attribute__((ext_vector_type(8))) short short8;
typedef __attribute__((ext_vector_type(4))) float floatx4;
typedef __attribute__((ext_vector_type(2))) float floatx2;
typedef __attribute__((ext_vector_type(4))) unsigned int u32x4;
typedef unsigned short u16;
typedef unsigned int u32;

__device__ __forceinline__ float us2f(u16 u) {
    unsigned int v = ((unsigned int)u) << 16;
    return __builtin_bit_cast(float, v);
}
__device__ __forceinline__ u16 f2us(float f) {
    unsigned int v = __builtin_bit_cast(unsigned int, f);
    v += 0x7FFFu + ((v >> 16) & 1u);
    return (u16)(v >> 16);
}
__device__ __forceinline__ float ldin(const void* p, long i, int bf) {
    return bf ? us2f(((const u16*)p)[i]) : ((const float*)p)[i];
}
__device__ __forceinline__ float sigm(float x) { return 1.0f / (1.0f + expf(-x)); }
__device__ __forceinline__ float fsig(float x) {
    return __builtin_amdgcn_rcpf(1.f + __expf(-x));
}
__device__ __forceinline__ float ftanh(float x) {
    x = fminf(10.f, fmaxf(-10.f, x));
    float t = __expf(2.f * x);
    return (t - 1.f) * __builtin_amdgcn_rcpf(t + 1.f);
}

// ---- dtype probe ----
__global__ void detect_k(const void* x, int* flag) {
    __shared__ int cnt;
    if (threadIdx.x == 0) cnt = 0;
    __syncthreads();
    u16 lo = ((const u16*)x)[threadIdx.x * 2];
    int e = (lo >> 7) & 0xFF;
    if (e >= 118 && e <= 131) atomicAdd(&cnt, 1);
    __syncthreads();
    if (threadIdx.x == 0) *flag = (cnt > 128) ? 1 : 0;
}
__global__ void castbf_k(const void* src, long off, u16* dst, long n, const int* flag) {
    long i = (long)blockIdx.x * 256 + threadIdx.x;
    if (i < n) dst[i] = (*flag) ? ((const u16*)src)[off + i] : f2us(((const float*)src)[off + i]);
}
__global__ void castf_k(const void* src, float* dst, long n, const int* flag) {
    long i = (long)blockIdx.x * 256 + threadIdx.x;
    if (i < n) dst[i] = ldin(src, i, *flag);
}
__global__ void zero_k(u32* p, long n) {
    long i = (long)blockIdx.x * 256 + threadIdx.x;
    if (i < n) p[i] = 0u;
}
__global__ void bias_sum_k(const void* bih, const void* bhh, float* out, const int* flag) {
    int i = blockIdx.x * 256 + threadIdx.x;
    if (i < G4) out[i] = ldin(bih, i, *flag) + ldin(bhh, i, *flag);
}
__global__ void wsum_k(const void* a, const void* b, u16* o, const int* flag) {
    int i = blockIdx.x * 256 + threadIdx.x;
    if (i < H2 * H2) o[i] = f2us(ldin(a, i, *flag) + ldin(b, i, *flag));
}
// Whh [1024,256] -> pre-swizzled MFMA B-frags for 2-WG (p) x 8-wave (w):
// n_g = gt*256 + p*128 + hh*64 + t4*16 + (ln&15), gt=w>>1, hh=w&1
__global__ void whh_frag_k(const void* Whh, u16* WF, const int* flag) {
    int i = blockIdx.x * 256 + threadIdx.x;
    if (i >= 262144) return;
    int j  = i & 7;
    int ln = (i >> 3) & 63;
    int c  = (i >> 9) & 7;
    int t4 = (i >> 12) & 3;
    int w  = (i >> 14) & 7;
    int p  = (i >> 17) & 1;
    int gt = w >> 1, hh = w & 1;
    int n_g = gt * 256 + p * 128 + hh * 64 + t4 * 16 + (ln & 15);
    int k   = c * 32 + (ln >> 4) * 8 + j;
    WF[i] = f2us(ldin(Whh, (long)n_g * 256 + k, *flag));
}

// ---------------------------------------------------------------------------
// GEMM: C[M,N] = A[M,K] @ W[N,K]^T (+bias). A/W internal bf16 or RAW (per flag).
// ---------------------------------------------------------------------------
#define BM 128
#define BN 128
#define BK 32
#define LDT 40

__global__ __launch_bounds__(256)
void gemm_bt(const void* __restrict__ A, long aOff, int lda,
             const void* __restrict__ W, int ldw,
             void* __restrict__ C, int ldc,
             const float* __restrict__ bias,
             int M, int N, int K, int outBf16,
             int aRaw, int wRaw, const int* __restrict__ flagp)
{
    __shared__ alignas(16) short As[BM * LDT];
    __shared__ alignas(16) short Bs[BN * LDT];
    const int bf = flagp ? *flagp : 1;
    const int af32 = aRaw && !bf;
    const int wf32 = wRaw && !bf;
    const u16* A16 = (const u16*)A;
    const float* AF = (const float*)A;
    const u16* W16 = (const u16*)W;
    const float* WFp = (const float*)W;

    const int tid  = threadIdx.x;
    const int m0   = blockIdx.y * BM;
    const int n0   = blockIdx.x * BN;
    const int lane = tid & 63;
    const int wave = tid >> 6;
    const int wm   = wave >> 1, wn = wave & 1;
    const int quad = lane >> 4, mrow = lane & 15;

    floatx4 acc[4][4];
#pragma unroll
    for (int i = 0; i < 4; ++i)
#pragma unroll
        for (int j = 0; j < 4; ++j) { floatx4 z4 = {0.f,0.f,0.f,0.f}; acc[i][j] = z4; }

    for (int k0 = 0; k0 < K; k0 += BK) {
#pragma unroll
        for (int cc = 0; cc < 2; ++cc) {
            int c   = tid + cc * 256;
            int row = c >> 2;
            int kc  = (c & 3) << 3;
            int gk  = k0 + kc;
            {   // A tile
                int gr = m0 + row;
                short8 v;
                size_t idx = (size_t)aOff + (size_t)gr * lda + gk;
                if (gr < M && gk + 8 <= K) {
                    if (af32) {
                        floatx4 f0 = *(const floatx4*)(AF + idx);
                        floatx4 f1 = *(const floatx4*)(AF + idx + 4);
#pragma unroll
                        for (int e = 0; e < 4; ++e) { v[e] = (short)f2us(f0[e]); v[4+e] = (short)f2us(f1[e]); }
                    } else {
                        v = *(const short8*)(A16 + idx);
                    }
                } else {
#pragma unroll
                    for (int e = 0; e < 8; ++e) {
                        u16 x = 0;
                        if (gr < M && (gk + e) < K)
                            x = af32 ? f2us(AF[idx + e]) : A16[idx + e];
                        v[e] = (short)x;
                    }
                }
                *(short8*)&As[row * LDT + kc] = v;
            }
            {   // W tile
                int gn = n0 + row;
                short8 v;
                size_t idx = (size_t)gn * ldw + gk;
                if (gn < N && gk + 8 <= K) {
                    if (wf32) {
                        floatx4 f0 = *(const floatx4*)(WFp + idx);
                        floatx4 f1 = *(const floatx4*)(WFp + idx + 4);
#pragma unroll
                        for (int e = 0; e < 4; ++e) { v[e] = (short)f2us(f0[e]); v[4+e] = (short)f2us(f1[e]); }
                    } else {
                        v = *(const short8*)(W16 + idx);
                    }
                } else {
#pragma unroll
                    for (int e = 0; e < 8; ++e) {
                        u16 x = 0;
                        if (gn < N && (gk + e) < K)
                            x = wf32 ? f2us(WFp[idx + e]) : W16[idx + e];
                        v[e] = (short)x;
                    }
                }
                *(short8*)&Bs[row * LDT + kc] = v;
            }
        }
        __syncthreads();

        short8 af[4], bfr[4];
#pragma unroll
        for (int i = 0; i < 4; ++i)
            af[i] = *(const short8*)&As[(wm * 64 + i * 16 + mrow) * LDT + quad * 8];
#pragma unroll
        for (int j = 0; j < 4; ++j)
            bfr[j] = *(const short8*)&Bs[(wn * 64 + j * 16 + mrow) * LDT + quad * 8];
#pragma unroll
        for (int i = 0; i < 4; ++i)
#pragma unroll
            for (int j = 0; j < 4; ++j)
                acc[i][j] = __builtin_amdgcn_mfma_f32_16x16x32_bf16(af[i], bfr[j], acc[i][j], 0, 0, 0);
        __syncthreads();
    }

#pragma unroll
    for (int i = 0; i < 4; ++i)
#pragma unroll
        for (int j = 0; j < 4; ++j)
#pragma unroll
            for (int r = 0; r < 4; ++r) {
                int row = m0 + wm * 64 + i * 16 + quad * 4 + r;
                int col = n0 + wn * 64 + j * 16 + mrow;
                if (row < M && col < N) {
                    float v = acc[i][j][r];
                    if (bias) v += bias[col];
                    if (outBf16) ((u16*)C)[(size_t)row * ldc + col] = f2us(v);
                    else         ((float*)C)[(size_t)row * ldc + col] = v;
                }
            }
}

// ---------------------------------------------------------------------------
// Cooperative LSTM v5: flat grid of C candidate WGs (512 thr). Each posts its
// XCC_ID to coord[blockIdx.x] (single writer/word, exchange+threadfence), then
// sweeps the table (ACQUIRE) and all WGs deterministically pair slots by XCD:
// same-XCD pairs first (fast relaxed-RMW sync in shared L2), leftovers get
// cross-XCD pairs (fenced r4-style sync). Pair k -> group k (k<G); rest exit.
// ---------------------------------------------------------------------------
__global__ __launch_bounds__(512, 1)
void lstm_coop3(const u16* __restrict__ xWf, const u16* __restrict__ xWb,
                const u16* __restrict__ WFf, const u16* __restrict__ WFb,
                int L,
                u16* __restrict__ hOut, int hStride,
                u16* __restrict__ cOut, int cStride,
                const int* __restrict__ lenp,
                int writeAtSource, int lastOnly, int seqBase,
                u32* __restrict__ hx32, u32* __restrict__ flags,
                u32* __restrict__ cnts, u32* __restrict__ coord,
                int G, int nb, int grpBase)
{
    const int C   = (int)gridDim.x;
    const int tid = threadIdx.x;
    __shared__ int shGrp, shP, shFast;
    __shared__ u32 tabS[64];

    // ---- bulletin-board pairing (one-time) ----
    if (tid == 0) {
        u32 my = (u32)(__builtin_amdgcn_s_getreg((3 << 11) | 20) & 0xF) + 1u; // XCC_ID+1
        __hip_atomic_exchange(coord + blockIdx.x, my, __ATOMIC_RELAXED, __HIP_MEMORY_SCOPE_AGENT);
        __threadfence();                          // write back to coherent point
        int done = 0; long guard = 0;
        while (!done) {
            done = 1;
            u32 v0 = __hip_atomic_load(coord, __ATOMIC_ACQUIRE, __HIP_MEMORY_SCOPE_AGENT); // inv
            tabS[0] = v0;
            if (v0 == 0) done = 0;
            for (int s = 1; s < C; ++s) {
                u32 v = __hip_atomic_load(coord + s, __ATOMIC_RELAXED, __HIP_MEMORY_SCOPE_AGENT);
                tabS[s] = v;
                if (v == 0) done = 0;
            }
            if (!done) { __builtin_amdgcn_s_sleep(4); if (++guard > (1 << 14)) break; }
        }
        // deterministic pairing from tabS
        const int s0 = (int)blockIdx.x;
        const u32 v0x = my;
        int r0 = 0, cnt0 = 0;
        for (int s = 0; s < C; ++s)
            if (tabS[s] == v0x) { if (s < s0) r0++; cnt0++; }
        int samePairsBefore = 0, totalSamePairs = 0, leftBefore = 0, amLeft = 0;
        for (u32 u = 1; u <= 16; ++u) {
            int cu = 0, lastSlot = -1;
            for (int s = 0; s < C; ++s)
                if (tabS[s] == u) { cu++; lastSlot = s; }
            if (u < v0x) samePairsBefore += cu >> 1;
            totalSamePairs += cu >> 1;
            if (cu & 1) {
                if (lastSlot >= 0 && lastSlot < s0) leftBefore++;
                if (lastSlot == s0) amLeft = 1;
            }
        }
        int grp = -1, p = 0, fast = 0;
        if (!amLeft && cnt0 > 0 && r0 < ((cnt0 >> 1) << 1)) {
            int k = samePairsBefore + (r0 >> 1);
            p = r0 & 1; fast = 1;
            if (k < G) grp = k;
        } else if (amLeft) {
            int k = totalSamePairs + (leftBefore >> 1);
            p = leftBefore & 1; fast = 0;
            if (k < G) grp = k;
        }
        shGrp = grp; shP = p; shFast = fast;
    }
    __syncthreads();
    const int grpL = shGrp;
    if (grpL < 0) return;                     // spare candidate
    const int p    = shP;
    const int fast = shFast;
    const int dir  = grpL / nb;
    const int bat  = grpL % nb;
    const int grpG = grpBase + grpL;

    const u16* xW = dir ? xWb : xWf;
    const u16* WF = dir ? WFb : WFf;
    u32* hx      = hx32 + (size_t)grpG * 2048;          // [2][8 seq][128 u32]
    u32* flagOwn = flags + (size_t)grpG * 128 + p * 64; // 256B apart
    u32* flagOth = flags + (size_t)grpG * 128 + (1 - p) * 64;
    u32* cnt     = cnts + (size_t)grpG * 64;

    const int w  = tid >> 6;
    const int ln = tid & 63;
    const int q  = ln >> 4, m = ln & 15;

    __shared__ float g_s[8 * 520];
    __shared__ u32 hls[8][68];

    // resident weights: 4 N-tiles x 8 K-chunks (128 regs/lane)
    short8 bw[4][8];
    {
        const u16* wb = WF + (size_t)(p * 8 + w) * 32 * 512 + ln * 8;
#pragma unroll
        for (int t4 = 0; t4 < 4; ++t4)
#pragma unroll
            for (int c = 0; c < 8; ++c)
                bw[t4][c] = *(const short8*)(wb + (size_t)(t4 * 8 + c) * 512);
    }

    const int seqU = tid >> 6;
    const int jh   = tid & 63;
    float c0 = 0.f, c1 = 0.f;

    u32 xw0, xw1, xw2, xw3;
    {
        int tt0 = dir ? (L - 1) : 0;
        const u16* xr = xW + ((size_t)(bat * 8 + seqU) * L + tt0) * G4 + p * 128 + jh * 2;
        xw0 = *(const u32*)(xr);
        xw1 = *(const u32*)(xr + 256);
        xw2 = *(const u32*)(xr + 512);
        xw3 = *(const u32*)(xr + 768);
    }

    for (int t = 0; t < L; ++t) {
        const int tt = dir ? (L - 1 - t) : t;
        // ---- A fragments ----
        short8 a[8];
        {
            short8 z = {0,0,0,0,0,0,0,0};
#pragma unroll
            for (int c = 0; c < 8; ++c) a[c] = z;
        }
        if (t > 0 && m < 8) {
            const int bsel = (t - 1) & 1;
            u32* hp = hx + bsel * 1024 + m * 128 + (1 - p) * 64;
            if (fast) {
                // same-L2: RMW reads are coherent and fresh
#pragma unroll
                for (int co = 0; co < 4; ++co) {
                    u32x4 vv;
#pragma unroll
                    for (int e = 0; e < 4; ++e)
                        vv[e] = __hip_atomic_fetch_add(hp + co * 16 + q * 4 + e, 0u,
                                                       __ATOMIC_RELAXED, __HIP_MEMORY_SCOPE_AGENT);
                    a[(1 - p) * 4 + co] = __builtin_bit_cast(short8, vv);
                }
            } else {
                // fenced path: ACQUIRE poll already invalidated caches -> plain loads fresh
#pragma unroll
                for (int co = 0; co < 4; ++co) {
                    u32x4 vv = *(const u32x4*)(hp + co * 16 + q * 4);
                    a[(1 - p) * 4 + co] = __builtin_bit_cast(short8, vv);
                }
            }
#pragma unroll
            for (int co = 0; co < 4; ++co) {
                u32x4 vv = *(const u32x4*)&hls[m][co * 16 + q * 4];
                a[p * 4 + co] = __builtin_bit_cast(short8, vv);
            }
        }
        floatx4 acc[4];
#pragma unroll
        for (int t4 = 0; t4 < 4; ++t4) { floatx4 z4 = {0.f,0.f,0.f,0.f}; acc[t4] = z4; }
#pragma unroll
        for (int t4 = 0; t4 < 4; ++t4)
#pragma unroll
            for (int c = 0; c < 8; ++c)
                acc[t4] = __builtin_amdgcn_mfma_f32_16x16x32_bf16(a[c], bw[t4][c], acc[t4], 0, 0, 0);
        if (q < 2) {
#pragma unroll
            for (int t4 = 0; t4 < 4; ++t4)
#pragma unroll
                for (int r = 0; r < 4; ++r)
                    g_s[(q * 4 + r) * 520 + w * 64 + t4 * 16 + m] = acc[t4][r];
        }
        __syncthreads();
        // ---- gate fuse + state update ----
        float hn0, hn1, cn0, cn1;
        {
            floatx2 gi = *(const floatx2*)&g_s[seqU * 520 + 0 * 128 + jh * 2];
            floatx2 gf = *(const floatx2*)&g_s[seqU * 520 + 1 * 128 + jh * 2];
            floatx2 gg = *(const floatx2*)&g_s[seqU * 520 + 2 * 128 + jh * 2];
            floatx2 go = *(const floatx2*)&g_s[seqU * 520 + 3 * 128 + jh * 2];
            float i0 = gi[0] + us2f((u16)(xw0 & 0xFFFF)), i1 = gi[1] + us2f((u16)(xw0 >> 16));
            float f0 = gf[0] + us2f((u16)(xw1 & 0xFFFF)), f1 = gf[1] + us2f((u16)(xw1 >> 16));
            float g0 = gg[0] + us2f((u16)(xw2 & 0xFFFF)), g1 = gg[1] + us2f((u16)(xw2 >> 16));
            float o0 = go[0] + us2f((u16)(xw3 & 0xFFFF)), o1 = go[1] + us2f((u16)(xw3 >> 16));
            cn0 = fsig(f0) * c0 + fsig(i0) * ftanh(g0);
            cn1 = fsig(f1) * c1 + fsig(i1) * ftanh(g1);
            hn0 = fsig(o0) * ftanh(cn0);
            hn1 = fsig(o1) * ftanh(cn1);
            c0 = cn0; c1 = cn1;
            u32 hpack = (u32)f2us(hn0) | ((u32)f2us(hn1) << 16);
            hls[seqU][jh] = hpack;
            __hip_atomic_exchange(hx + (t & 1) * 1024 + seqU * 128 + p * 64 + jh, hpack,
                                  __ATOMIC_RELAXED, __HIP_MEMORY_SCOPE_AGENT);
        }
        // prefetch next xW + deferred output stores
        if (t + 1 < L) {
            int tt2 = dir ? (L - 2 - t) : (t + 1);
            const u16* xr = xW + ((size_t)(bat * 8 + seqU) * L + tt2) * G4 + p * 128 + jh * 2;
            xw0 = *(const u32*)(xr);
            xw1 = *(const u32*)(xr + 256);
            xw2 = *(const u32*)(xr + 512);
            xw3 = *(const u32*)(xr + 768);
        }
        if (!lastOnly) {
            int wr = writeAtSource ? tt : t;
            float mk = (lenp && wr >= lenp[bat * 8 + seqU]) ? 0.f : 1.f;
            size_t ro = (size_t)(bat * 8 + seqU) * L + wr;
            u32 hp2 = (u32)f2us(hn0 * mk) | ((u32)f2us(hn1 * mk) << 16);
            *(u32*)(hOut + ro * hStride + dir * RR + p * 128 + jh * 2) = hp2;
            if (cOut) {
                u32 cp2 = (u32)f2us(cn0 * mk) | ((u32)f2us(cn1 * mk) << 16);
                *(u32*)(cOut + ro * cStride + dir * RR + p * 128 + jh * 2) = cp2;
            }
        } else if (t == L - 1) {
            size_t ro = (size_t)(seqBase + bat * 8 + seqU);
            u32 hp2 = (u32)f2us(hn0) | ((u32)f2us(hn1) << 16);
            *(u32*)(hOut + ro * hStride + dir * RR + p * 128 + jh * 2) = hp2;
        }
        // ---- drain all waves' h publishes, then sync ----
        __syncthreads();     // each wave waits vmcnt(0) before s_barrier
        if (tid == 0) {
            if (fast) {
                __hip_atomic_exchange(flagOwn, (u32)(t + 1),
                                      __ATOMIC_RELAXED, __HIP_MEMORY_SCOPE_AGENT);
                long g = 0;
                while (__hip_atomic_fetch_add(flagOth, 0u,
                           __ATOMIC_RELAXED, __HIP_MEMORY_SCOPE_AGENT) < (u32)(t + 1)) {
                    __builtin_amdgcn_s_sleep(1);
                    if (++g > (1 << 20)) break;
                }
            } else {
                __threadfence();                               // wbl2: h + flag lines
                __hip_atomic_fetch_add(cnt, 1u, __ATOMIC_RELEASE, __HIP_MEMORY_SCOPE_AGENT);
                u32 tgt = 2u * (u32)(t + 1);
                long g = 0;
                while (__hip_atomic_load(cnt, __ATOMIC_ACQUIRE, __HIP_MEMORY_SCOPE_AGENT) < tgt) {
                    __builtin_amdgcn_s_sleep(1);
                    if (++g > (1 << 20)) break;
                }
            }
        }
        __syncthreads();
    }
}

// ------------------------- small fused kernels -----------------------------
__global__ void hprev_k(const u16* __restrict__ G, u16* __restrict__ Hp) {
    int idx = blockIdx.x * 256 + threadIdx.x;
    if (idx < BT * H2) {
        int r = idx >> 9, d = idx & 511;
        int t = r & (TT - 1);
        Hp[idx] = (t == 0) ? (u16)0 : G[(size_t)(r - 1) * G4 + d];
    }
}
__global__ void s_k(const float* __restrict__ e, const u16* __restrict__ mB,
                    u16* __restrict__ sB) {
    int i = blockIdx.x * 256 + threadIdx.x;
    if (i < BT * H2) sB[i] = f2us(sigm(e[i]) * tanhf(us2f(mB[i])));
}
__global__ void z_k(const float* __restrict__ cWh, const float* __restrict__ cWu,
                    const float* __restrict__ Wv, float* __restrict__ z) {
    int idx = blockIdx.x * 256 + threadIdx.x;
    if (idx >= BT * SS) return;
    int r = idx >> 5, s = idx & 31;
    int b = r >> 9;
    const float* ph = cWh + (size_t)r * MDU_;
    const float* pu = cWu + (size_t)(b * SS + s) * MDU_;
    float acc = 0.f;
    for (int j = 0; j < MDU_; ++j) acc += tanhf(ph[j] + pu[j]) * Wv[j];
    z[idx] = acc;
}
__global__ void zhat_k(const float* __restrict__ sW, const float* __restrict__ cWh,
                       const float* __restrict__ Wv, float* __restrict__ zhat) {
    int r = blockIdx.x * 256 + threadIdx.x;
    if (r >= BT) return;
    float acc = 0.f;
    const float* ps = sW + (size_t)r * MDU_;
    const float* ph = cWh + (size_t)r * MDU_;
    for (int j = 0; j < MDU_; ++j) acc += tanhf(ps[j] + ph[j]) * Wv[j];
    zhat[r] = acc;
}
__global__ __launch_bounds__(64)
void attn_mix_k(const float* __restrict__ z, const float* __restrict__ zhat,
                const u16* __restrict__ U, const u16* __restrict__ sB,
                u16* __restrict__ G) {
    int r = blockIdx.x;
    int lane = threadIdx.x;
    int b = r >> 9;
    __shared__ float alpha[SS];
    float zv = (lane < SS) ? z[(size_t)r * SS + lane] : -1e30f;
    float mx = zv;
    for (int o = 32; o > 0; o >>= 1) mx = fmaxf(mx, __shfl_xor(mx, o));
    float ez = (lane < SS) ? expf(zv - mx) : 0.f;
    float s1 = ez;
    for (int o = 32; o > 0; o >>= 1) s1 += __shfl_xor(s1, o);
    float zh = zhat[r];
    float mx2 = fmaxf(mx, zh);
    float denom = s1 * expf(mx - mx2) + expf(zh - mx2);
    float beta = expf(zh - mx2) / denom;
    if (lane < SS) alpha[lane] = ez / s1;
    __syncthreads();
    for (int d = lane; d < H2; d += 64) {
        float cv = 0.f;
#pragma unroll 8
        for (int s2 = 0; s2 < SS; ++s2)
            cv += alpha[s2] * us2f(U[(size_t)(b * SS + s2) * H2 + d]);
        float sv = us2f(sB[(size_t)r * H2 + d]);
        G[(size_t)r * G4 + H2 + d] = f2us(beta * sv + (1.f - beta) * cv);
    }
}
__global__ __launch_bounds__(256)
void logit_k(const u16* __restrict__ G, const u16* __restrict__ Mb,
             const u16* __restrict__ Wout, const float* __restrict__ boutF,
             void* __restrict__ out, const int* __restrict__ flag) {
    int r = blockIdx.x * 4 + (threadIdx.x >> 6);
    if (r >= BT) return;
    int lane = threadIdx.x & 63;
    float acc[TAGS_] = {0, 0, 0, 0, 0, 0, 0};
    for (int k = lane; k < 1536; k += 64) {
        float v = (k < G4) ? us2f(G[(size_t)r * G4 + k]) : us2f(Mb[(size_t)r * H2 + (k - G4)]);
#pragma unroll
        for (int tg = 0; tg < TAGS_; ++tg) acc[tg] += v * us2f(Wout[tg * 1536 + k]);
    }
#pragma unroll
    for (int tg = 0; tg < TAGS_; ++tg) {
        float s = acc[tg];
        for (int o = 32; o > 0; o >>= 1) s += __shfl_xor(s, o);
        acc[tg] = s;
    }
    if (lane == 0) {
        int bf = *flag;
#pragma unroll
        for (int tg = 0; tg < TAGS_; ++tg) {
            float v = acc[tg] + boutF[tg];
            if (bf) ((u16*)out)[(size_t)r * TAGS_ + tg] = f2us(v);
            else    ((float*)out)[(size_t)r * TAGS_ + tg] = v;
        }
    }
}

// ---------------------------------------------------------------------------
extern "C" void kernel_launch(void* const* d_in, const int* in_sizes, int n_in,
                              void* d_out, int out_size, void* d_ws, size_t ws_size,
                              hipStream_t stream)
{
    const void* x_text = d_in[0];
    const void* x_syn  = d_in[1];
    const int* len_ctx = (const int*)d_in[3];
    const void *Wih[6], *Whh[6], *bih[6], *bhh[6];
    for (int l = 0; l < 6; ++l) {
        Wih[l] = d_in[5 + l * 4 + 0];
        Whh[l] = d_in[5 + l * 4 + 1];
        bih[l] = d_in[5 + l * 4 + 2];
        bhh[l] = d_in[5 + l * 4 + 3];
    }
    const void* W_cWh = d_in[29];
    const void* W_cWu = d_in[30];
    const void* W_v   = d_in[31];
    const void* W_sWh = d_in[32];
    const void* W_sWu = d_in[33];
    const void* W_Ws  = d_in[34];
    const void* W_out = d_in[35];
    const void* b_out = d_in[36];
    (void)in_sizes; (void)n_in; (void)out_size; (void)ws_size;

    char* ws = (char*)d_ws;
    size_t off = 0;
    auto alloc = [&](size_t bytes) -> void* {
        void* p = ws + off;
        off += (bytes + 255) & ~(size_t)255;
        return p;
    };
    int*   flagB  = (int*)alloc(256);
    float* bsum[6];
    for (int l = 0; l < 6; ++l) bsum[l] = (float*)alloc((size_t)G4 * 4);
    u16*   WsumB  = (u16*)alloc((size_t)H2 * H2 * 2);
    u16*   Ub     = (u16*)alloc((size_t)NSEQ * H2 * 2);
    u16*   Gb     = (u16*)alloc((size_t)BT * G4 * 2);
    u16*   mMb    = (u16*)alloc((size_t)BT * H2 * 2);
    float* cWhB   = (float*)alloc((size_t)BT * MDU_ * 4);
    float* cWuB   = (float*)alloc((size_t)NSEQ * MDU_ * 4);
    float* sWB    = (float*)alloc((size_t)BT * MDU_ * 4);
    float* zB     = (float*)alloc((size_t)BT * SS * 4);
    float* zhatB  = (float*)alloc((size_t)BT * 4);
    u16*   Wout16 = (u16*)alloc((size_t)TAGS_ * 1536 * 2);
    float* WvF    = (float*)alloc((size_t)MDU_ * 4);
    float* boutF  = (float*)alloc((size_t)TAGS_ * 4);
    u16*   WF[6];
    for (int l = 0; l < 6; ++l) WF[l] = (u16*)alloc((size_t)G4 * RR * 2);
    // sync zone: coord(6*128) + flags(128*128) + cnts(128*64) u32, zeroed each launch
    u32*   coordZ = (u32*)alloc((size_t)(6 * 128) * 4);
    u32*   flagsZ = (u32*)alloc((size_t)(128 * 128) * 4);
    u32*   cntsZ  = (u32*)alloc((size_t)(128 * 64) * 4);
    u32*   hx32   = (u32*)alloc((size_t)128 * 2048 * 4);
    char*  BIG    = (char*)alloc((size_t)24 * MB1);

    u16*   bufA  = (u16*)BIG;                       // 8MB xW fwd
    u16*   bufB  = (u16*)(BIG + (size_t)8 * MB1);   // 8MB xW bwd
    u16*   HprevB = (u16*)BIG;                      // phase C overlays
    float* eBuf   = (float*)(BIG + (size_t)4 * MB1);
    u16*   sBuf   = (u16*)(BIG + (size_t)12 * MB1);
    u16*   mxWf  = (u16*)BIG;                       // phase D overlays
    u16*   mxWb  = (u16*)(BIG + (size_t)8 * MB1);

    auto cgrid = [](long n) { return dim3((unsigned)((n + 255) / 256)); };

    // ---- prep ----
    detect_k<<<dim3(1), dim3(256), 0, stream>>>(x_text, flagB);
    zero_k<<<cgrid(6 * 128 + 128 * 128 + 128 * 64), dim3(256), 0, stream>>>(coordZ, 6 * 128 + 128 * 128 + 128 * 64);
    castbf_k<<<cgrid(TAGS_ * 1536), dim3(256), 0, stream>>>(W_out, 0, Wout16, TAGS_ * 1536, flagB);
    castf_k<<<cgrid(MDU_), dim3(256), 0, stream>>>(W_v, WvF, MDU_, flagB);
    castf_k<<<cgrid(TAGS_), dim3(256), 0, stream>>>(b_out, boutF, TAGS_, flagB);
    for (int l = 0; l < 6; ++l) {
        bias_sum_k<<<dim3(4), dim3(256), 0, stream>>>(bih[l], bhh[l], bsum[l], flagB);
        whh_frag_k<<<dim3(1024), dim3(256), 0, stream>>>(Whh[l], WF[l], flagB);
    }
    wsum_k<<<cgrid(H2 * H2), dim3(256), 0, stream>>>(W_sWh, W_sWu, WsumB, flagB);

    // ---- phase A: synopsis (4 chunks of 64 seqs) -> U ----
    for (int c = 0; c < NSEQ / SCH; ++c) {
        long aOff = (long)c * SCH * JJ * DD;
        gemm_bt<<<dim3(8, (SCH * JJ) / BM), dim3(256), 0, stream>>>(
            x_syn, aOff, DD, Wih[2], DD, bufA, G4, bsum[2], SCH * JJ, G4, DD, 1, 1, 1, flagB);
        gemm_bt<<<dim3(8, (SCH * JJ) / BM), dim3(256), 0, stream>>>(
            x_syn, aOff, DD, Wih[3], DD, bufB, G4, bsum[3], SCH * JJ, G4, DD, 1, 1, 1, flagB);
        lstm_coop3<<<dim3(64, 1, 1), dim3(512), 0, stream>>>(
            bufA, bufB, WF[2], WF[3], JJ,
            Ub, H2, (u16*)nullptr, 0, (const int*)nullptr,
            0, 1, c * SCH, hx32, flagsZ, cntsZ, coordZ + c * 128,
            16, 8, 2 + c * 16);
    }

    // ---- phase B: context layer-1 -> H (Gb left), m (mMb) ----
    gemm_bt<<<dim3(8, 32), dim3(256), 0, stream>>>(
        x_text, 0, DD, Wih[0], DD, bufA, G4, bsum[0], BT, G4, DD, 1, 1, 1, flagB);
    gemm_bt<<<dim3(8, 32), dim3(256), 0, stream>>>(
        x_text, 0, DD, Wih[1], DD, bufB, G4, bsum[1], BT, G4, DD, 1, 1, 1, flagB);
    lstm_coop3<<<dim3(32, 1, 1), dim3(512), 0, stream>>>(
        bufA, bufB, WF[0], WF[1], TT,
        Gb, G4, mMb, H2, len_ctx, 0, 0, 0, hx32, flagsZ, cntsZ, coordZ + 4 * 128,
        2, 1, 0);

    // ---- phase C: attention ----
    gemm_bt<<<dim3(1, 32), dim3(256), 0, stream>>>(
        Gb, 0, G4, W_cWh, H2, cWhB, MDU_, nullptr, BT, MDU_, H2, 0, 0, 1, flagB);
    gemm_bt<<<dim3(1, 2), dim3(256), 0, stream>>>(
        Ub, 0, H2, W_cWu, H2, cWuB, MDU_, nullptr, NSEQ, MDU_, H2, 0, 0, 1, flagB);
    hprev_k<<<cgrid(BT * H2), dim3(256), 0, stream>>>(Gb, HprevB);
    gemm_bt<<<dim3(4, 32), dim3(256), 0, stream>>>(
        HprevB, 0, H2, WsumB, H2, eBuf, H2, nullptr, BT, H2, H2, 0, 0, 0, nullptr);
    s_k<<<cgrid(BT * H2), dim3(256), 0, stream>>>(eBuf, mMb, sBuf);
    gemm_bt<<<dim3(1, 32), dim3(256), 0, stream>>>(
        sBuf, 0, H2, W_Ws, H2, sWB, MDU_, nullptr, BT, MDU_, H2, 0, 0, 1, flagB);
    z_k<<<cgrid(BT * SS), dim3(256), 0, stream>>>(cWhB, cWuB, WvF, zB);
    zhat_k<<<cgrid(BT), dim3(256), 0, stream>>>(sWB, cWhB, WvF, zhatB);
    attn_mix_k<<<dim3(BT), dim3(64), 0, stream>>>(zB, zhatB, Ub, sBuf, Gb);

    // ---- phase D: layer-2 LSTMs over G -> M (into mMb) ----
    gemm_bt<<<dim3(8, 32), dim3(256), 0, stream>>>(
        Gb, 0, G4, Wih[4], G4, mxWf, G4, bsum[4], BT, G4, G4, 1, 0, 1, flagB);
    gemm_bt<<<dim3(8, 32), dim3(256), 0, stream>>>(
        Gb, 0, G4, Wih[5], G4, mxWb, G4, bsum[5], BT, G4, G4, 1, 0, 1, flagB);
    lstm_coop3<<<dim3(32, 1, 1), dim3(512), 0, stream>>>(
        mxWf, mxWb, WF[4], WF[5], TT,
        mMb, H2, (u16*)nullptr, 0, (const int*)nullptr, 1, 0, 0, hx32, flagsZ, cntsZ,
        coordZ + 5 * 128, 2, 1, 66);

    // ---- output ----
    logit_k<<<dim3(BT / 4), dim3(256), 0, stream>>>(Gb, mMb, Wout16, boutF, d_out, flagB);
}

// Round 9
// 12568.002 us; speedup vs baseline: 8.2449x; 8.2093x over previous
//
#include <hip/hip_runtime.h>
#include <math.h>
#include <stddef.h>

// ---------------------------------------------------------------------------
// ATT_SYN: bi-LSTM encoder + synopsis attention + 2nd bi-LSTM + tag head.
// B=8 T=512 S=32 J=64 D=400 R=256 MDU=100 TAGS=7
// Recurrence (r8 lesson: NO cross-WG sync is trustworthy on gfx950): ONE
// 1024-thread WG per (direction, 8-seq batch) holds the ENTIRE 1024x256 bf16
// Whh resident in registers (16 waves x 128 VGPR/lane = 512KB) and exchanges
// h through LDS with plain __syncthreads. No atomics, no placement deps.
// ---------------------------------------------------------------------------

#define BB 8
#define TT 512
#define SS 32
#define JJ 64
#define DD 400
#define RR 256
#define G4 1024
#define H2 512
#define MDU_ 100
#define TAGS_ 7
#define BT (BB*TT)
#define NSEQ (BB*SS)
#define SCH 64
#define MB1 (1024*1024)

typedef __attribute__((ext_vector_type(8))) short short8;
typedef __attribute__((ext_vector_type(4))) float floatx4;
typedef __attribute__((ext_vector_type(2))) float floatx2;
typedef __attribute__((ext_vector_type(4))) unsigned int u32x4;
typedef unsigned short u16;
typedef unsigned int u32;

__device__ __forceinline__ float us2f(u16 u) {
    unsigned int v = ((unsigned int)u) << 16;
    return __builtin_bit_cast(float, v);
}
__device__ __forceinline__ u16 f2us(float f) {
    unsigned int v = __builtin_bit_cast(unsigned int, f);
    v += 0x7FFFu + ((v >> 16) & 1u);
    return (u16)(v >> 16);
}
__device__ __forceinline__ float ldin(const void* p, long i, int bf) {
    return bf ? us2f(((const u16*)p)[i]) : ((const float*)p)[i];
}
__device__ __forceinline__ float sigm(float x) { return 1.0f / (1.0f + expf(-x)); }
__device__ __forceinline__ float fsig(float x) {
    return __builtin_amdgcn_rcpf(1.f + __expf(-x));
}
__device__ __forceinline__ float ftanh(float x) {
    x = fminf(10.f, fmaxf(-10.f, x));
    float t = __expf(2.f * x);
    return (t - 1.f) * __builtin_amdgcn_rcpf(t + 1.f);
}

// ---- dtype probe ----
__global__ void detect_k(const void* x, int* flag) {
    __shared__ int cnt;
    if (threadIdx.x == 0) cnt = 0;
    __syncthreads();
    u16 lo = ((const u16*)x)[threadIdx.x * 2];
    int e = (lo >> 7) & 0xFF;
    if (e >= 118 && e <= 131) atomicAdd(&cnt, 1);
    __syncthreads();
    if (threadIdx.x == 0) *flag = (cnt > 128) ? 1 : 0;
}
__global__ void castbf_k(const void* src, long off, u16* dst, long n, const int* flag) {
    long i = (long)blockIdx.x * 256 + threadIdx.x;
    if (i < n) dst[i] = (*flag) ? ((const u16*)src)[off + i] : f2us(((const float*)src)[off + i]);
}
__global__ void castf_k(const void* src, float* dst, long n, const int* flag) {
    long i = (long)blockIdx.x * 256 + threadIdx.x;
    if (i < n) dst[i] = ldin(src, i, *flag);
}
__global__ void bias_sum_k(const void* bih, const void* bhh, float* out, const int* flag) {
    int i = blockIdx.x * 256 + threadIdx.x;
    if (i < G4) out[i] = ldin(bih, i, *flag) + ldin(bhh, i, *flag);
}
__global__ void wsum_k(const void* a, const void* b, u16* o, const int* flag) {
    int i = blockIdx.x * 256 + threadIdx.x;
    if (i < H2 * H2) o[i] = f2us(ldin(a, i, *flag) + ldin(b, i, *flag));
}
// Whh [1024,256] -> pre-swizzled MFMA B-frags for the 16-wave solo layout:
// i = (((w*4 + t4)*8 + c)*64 + ln)*8 + j,  w=0..15
// n_g = w*64 + t4*16 + (ln&15);  k = c*32 + (ln>>4)*8 + j
__global__ void whh_frag_k(const void* Whh, u16* WF, const int* flag) {
    int i = blockIdx.x * 256 + threadIdx.x;
    if (i >= 262144) return;
    int j  = i & 7;
    int ln = (i >> 3) & 63;
    int c  = (i >> 9) & 7;
    int t4 = (i >> 12) & 3;
    int w  = (i >> 14) & 15;
    int n_g = w * 64 + t4 * 16 + (ln & 15);
    int k   = c * 32 + (ln >> 4) * 8 + j;
    WF[i] = f2us(ldin(Whh, (long)n_g * 256 + k, *flag));
}

// ---------------------------------------------------------------------------
// GEMM: C[M,N] = A[M,K] @ W[N,K]^T (+bias). A/W internal bf16 or RAW (per flag).
// ---------------------------------------------------------------------------
#define BM 128
#define BN 128
#define BK 32
#define LDT 40

__global__ __launch_bounds__(256)
void gemm_bt(const void* __restrict__ A, long aOff, int lda,
             const void* __restrict__ W, int ldw,
             void* __restrict__ C, int ldc,
             const float* __restrict__ bias,
             int M, int N, int K, int outBf16,
             int aRaw, int wRaw, const int* __restrict__ flagp)
{
    __shared__ alignas(16) short As[BM * LDT];
    __shared__ alignas(16) short Bs[BN * LDT];
    const int bf = flagp ? *flagp : 1;
    const int af32 = aRaw && !bf;
    const int wf32 = wRaw && !bf;
    const u16* A16 = (const u16*)A;
    const float* AF = (const float*)A;
    const u16* W16 = (const u16*)W;
    const float* WFp = (const float*)W;

    const int tid  = threadIdx.x;
    const int m0   = blockIdx.y * BM;
    const int n0   = blockIdx.x * BN;
    const int lane = tid & 63;
    const int wave = tid >> 6;
    const int wm   = wave >> 1, wn = wave & 1;
    const int quad = lane >> 4, mrow = lane & 15;

    floatx4 acc[4][4];
#pragma unroll
    for (int i = 0; i < 4; ++i)
#pragma unroll
        for (int j = 0; j < 4; ++j) { floatx4 z4 = {0.f,0.f,0.f,0.f}; acc[i][j] = z4; }

    for (int k0 = 0; k0 < K; k0 += BK) {
#pragma unroll
        for (int cc = 0; cc < 2; ++cc) {
            int c   = tid + cc * 256;
            int row = c >> 2;
            int kc  = (c & 3) << 3;
            int gk  = k0 + kc;
            {   // A tile
                int gr = m0 + row;
                short8 v;
                size_t idx = (size_t)aOff + (size_t)gr * lda + gk;
                if (gr < M && gk + 8 <= K) {
                    if (af32) {
                        floatx4 f0 = *(const floatx4*)(AF + idx);
                        floatx4 f1 = *(const floatx4*)(AF + idx + 4);
#pragma unroll
                        for (int e = 0; e < 4; ++e) { v[e] = (short)f2us(f0[e]); v[4+e] = (short)f2us(f1[e]); }
                    } else {
                        v = *(const short8*)(A16 + idx);
                    }
                } else {
#pragma unroll
                    for (int e = 0; e < 8; ++e) {
                        u16 x = 0;
                        if (gr < M && (gk + e) < K)
                            x = af32 ? f2us(AF[idx + e]) : A16[idx + e];
                        v[e] = (short)x;
                    }
                }
                *(short8*)&As[row * LDT + kc] = v;
            }
            {   // W tile
                int gn = n0 + row;
                short8 v;
                size_t idx = (size_t)gn * ldw + gk;
                if (gn < N && gk + 8 <= K) {
                    if (wf32) {
                        floatx4 f0 = *(const floatx4*)(WFp + idx);
                        floatx4 f1 = *(const floatx4*)(WFp + idx + 4);
#pragma unroll
                        for (int e = 0; e < 4; ++e) { v[e] = (short)f2us(f0[e]); v[4+e] = (short)f2us(f1[e]); }
                    } else {
                        v = *(const short8*)(W16 + idx);
                    }
                } else {
#pragma unroll
                    for (int e = 0; e < 8; ++e) {
                        u16 x = 0;
                        if (gn < N && (gk + e) < K)
                            x = wf32 ? f2us(WFp[idx + e]) : W16[idx + e];
                        v[e] = (short)x;
                    }
                }
                *(short8*)&Bs[row * LDT + kc] = v;
            }
        }
        __syncthreads();

        short8 af[4], bfr[4];
#pragma unroll
        for (int i = 0; i < 4; ++i)
            af[i] = *(const short8*)&As[(wm * 64 + i * 16 + mrow) * LDT + quad * 8];
#pragma unroll
        for (int j = 0; j < 4; ++j)
            bfr[j] = *(const short8*)&Bs[(wn * 64 + j * 16 + mrow) * LDT + quad * 8];
#pragma unroll
        for (int i = 0; i < 4; ++i)
#pragma unroll
            for (int j = 0; j < 4; ++j)
                acc[i][j] = __builtin_amdgcn_mfma_f32_16x16x32_bf16(af[i], bfr[j], acc[i][j], 0, 0, 0);
        __syncthreads();
    }

#pragma unroll
    for (int i = 0; i < 4; ++i)
#pragma unroll
        for (int j = 0; j < 4; ++j)
#pragma unroll
            for (int r = 0; r < 4; ++r) {
                int row = m0 + wm * 64 + i * 16 + quad * 4 + r;
                int col = n0 + wn * 64 + j * 16 + mrow;
                if (row < M && col < N) {
                    float v = acc[i][j][r];
                    if (bias) v += bias[col];
                    if (outBf16) ((u16*)C)[(size_t)row * ldc + col] = f2us(v);
                    else         ((float*)C)[(size_t)row * ldc + col] = v;
                }
            }
}

// ---------------------------------------------------------------------------
// Solo LSTM: grid (2 dirs, nb batches), 1024 threads = 16 waves. Wave w holds
// Whh rows [w*64, w*64+64) as resident B-frags (128 VGPR/lane; 512KB/WG
// total). Per step: each wave 32 MFMAs (M=8 seqs, N=64, K=256); gates fused
// via LDS g_s; h kept packed-bf16 in LDS hls. Sync = __syncthreads only.
// ---------------------------------------------------------------------------
__global__ __launch_bounds__(1024)
void lstm_solo(const u16* __restrict__ xWf, const u16* __restrict__ xWb,
               const u16* __restrict__ WFf, const u16* __restrict__ WFb,
               int L,
               u16* __restrict__ hOut, int hStride,
               u16* __restrict__ cOut, int cStride,
               const int* __restrict__ lenp,
               int writeAtSource, int lastOnly, int seqBase)
{
    const int dir = blockIdx.x;
    const int bat = blockIdx.y;
    const int tid = threadIdx.x;
    const int w   = tid >> 6;          // wave 0..15 -> gate cols [w*64, w*64+64)
    const int ln  = tid & 63;
    const int q   = ln >> 4, m = ln & 15;
    const u16* xW = dir ? xWb : xWf;
    const u16* WF = dir ? WFb : WFf;

    __shared__ float g_s[8 * 1032];    // [seq][1024 gates, pad 1032]
    __shared__ u32 hls[8][132];        // [seq][128 u32 = 256 bf16 h, pad 132]

    // resident weights: 4 N-tiles x 8 K-chunks = 128 VGPRs
    short8 bw[4][8];
    {
        const u16* wb = WF + (size_t)w * 32 * 512 + (size_t)ln * 8;
#pragma unroll
        for (int t4 = 0; t4 < 4; ++t4)
#pragma unroll
            for (int c = 0; c < 8; ++c)
                bw[t4][c] = *(const short8*)(wb + (size_t)(t4 * 8 + c) * 512);
    }

    const int seqU = tid >> 7;         // fuse phase: seq 0..7
    const int jh   = tid & 127;        // unit pair (units 2jh, 2jh+1)
    float c0 = 0.f, c1 = 0.f;

    // prefetch xW gate rows for t=0
    u32 xw0, xw1, xw2, xw3;
    {
        int tt0 = dir ? (L - 1) : 0;
        const u16* xr = xW + ((size_t)(bat * 8 + seqU) * L + tt0) * G4 + jh * 2;
        xw0 = *(const u32*)(xr);
        xw1 = *(const u32*)(xr + 256);
        xw2 = *(const u32*)(xr + 512);
        xw3 = *(const u32*)(xr + 768);
    }

    for (int t = 0; t < L; ++t) {
        const int tt = dir ? (L - 1 - t) : t;
        // ---- A fragments from LDS h (bf16 packed) ----
        short8 a[8];
        {
            short8 z = {0,0,0,0,0,0,0,0};
#pragma unroll
            for (int c = 0; c < 8; ++c) a[c] = z;
        }
        if (t > 0 && m < 8) {
#pragma unroll
            for (int c = 0; c < 8; ++c) {
                u32x4 vv = *(const u32x4*)&hls[m][c * 16 + q * 4];
                a[c] = __builtin_bit_cast(short8, vv);
            }
        }
        floatx4 acc[4];
#pragma unroll
        for (int t4 = 0; t4 < 4; ++t4) { floatx4 z4 = {0.f,0.f,0.f,0.f}; acc[t4] = z4; }
#pragma unroll
        for (int t4 = 0; t4 < 4; ++t4)
#pragma unroll
            for (int c = 0; c < 8; ++c)
                acc[t4] = __builtin_amdgcn_mfma_f32_16x16x32_bf16(a[c], bw[t4][c], acc[t4], 0, 0, 0);
        // C layout: seq row = q*4+r (q<2), col = w*64 + t4*16 + m
        if (q < 2) {
#pragma unroll
            for (int t4 = 0; t4 < 4; ++t4)
#pragma unroll
                for (int r = 0; r < 4; ++r)
                    g_s[(q * 4 + r) * 1032 + w * 64 + t4 * 16 + m] = acc[t4][r];
        }
        __syncthreads();
        // ---- gate fuse + state update: thread -> (seqU, units 2jh, 2jh+1) ----
        float hn0, hn1, cn0, cn1;
        {
            floatx2 gi = *(const floatx2*)&g_s[seqU * 1032 + 0 * 256 + jh * 2];
            floatx2 gf = *(const floatx2*)&g_s[seqU * 1032 + 1 * 256 + jh * 2];
            floatx2 gg = *(const floatx2*)&g_s[seqU * 1032 + 2 * 256 + jh * 2];
            floatx2 go = *(const floatx2*)&g_s[seqU * 1032 + 3 * 256 + jh * 2];
            float i0 = gi[0] + us2f((u16)(xw0 & 0xFFFF)), i1 = gi[1] + us2f((u16)(xw0 >> 16));
            float f0 = gf[0] + us2f((u16)(xw1 & 0xFFFF)), f1 = gf[1] + us2f((u16)(xw1 >> 16));
            float g0 = gg[0] + us2f((u16)(xw2 & 0xFFFF)), g1 = gg[1] + us2f((u16)(xw2 >> 16));
            float o0 = go[0] + us2f((u16)(xw3 & 0xFFFF)), o1 = go[1] + us2f((u16)(xw3 >> 16));
            cn0 = fsig(f0) * c0 + fsig(i0) * ftanh(g0);
            cn1 = fsig(f1) * c1 + fsig(i1) * ftanh(g1);
            hn0 = fsig(o0) * ftanh(cn0);
            hn1 = fsig(o1) * ftanh(cn1);
            c0 = cn0; c1 = cn1;
            hls[seqU][jh] = (u32)f2us(hn0) | ((u32)f2us(hn1) << 16);
        }
        // prefetch next xW row (latency hidden behind stores + barrier)
        if (t + 1 < L) {
            int tt2 = dir ? (L - 2 - t) : (t + 1);
            const u16* xr = xW + ((size_t)(bat * 8 + seqU) * L + tt2) * G4 + jh * 2;
            xw0 = *(const u32*)(xr);
            xw1 = *(const u32*)(xr + 256);
            xw2 = *(const u32*)(xr + 512);
            xw3 = *(const u32*)(xr + 768);
        }
        // output stores
        if (!lastOnly) {
            int wr = writeAtSource ? tt : t;
            float mk = (lenp && wr >= lenp[bat * 8 + seqU]) ? 0.f : 1.f;
            size_t ro = (size_t)(bat * 8 + seqU) * L + wr;
            u32 hp2 = (u32)f2us(hn0 * mk) | ((u32)f2us(hn1 * mk) << 16);
            *(u32*)(hOut + ro * hStride + dir * RR + jh * 2) = hp2;
            if (cOut) {
                u32 cp2 = (u32)f2us(cn0 * mk) | ((u32)f2us(cn1 * mk) << 16);
                *(u32*)(cOut + ro * cStride + dir * RR + jh * 2) = cp2;
            }
        } else if (t == L - 1) {
            size_t ro = (size_t)(seqBase + bat * 8 + seqU);
            u32 hp2 = (u32)f2us(hn0) | ((u32)f2us(hn1) << 16);
            *(u32*)(hOut + ro * hStride + dir * RR + jh * 2) = hp2;
        }
        __syncthreads();   // hls writes visible before next step's A reads
    }
}

// ------------------------- small fused kernels -----------------------------
__global__ void hprev_k(const u16* __restrict__ G, u16* __restrict__ Hp) {
    int idx = blockIdx.x * 256 + threadIdx.x;
    if (idx < BT * H2) {
        int r = idx >> 9, d = idx & 511;
        int t = r & (TT - 1);
        Hp[idx] = (t == 0) ? (u16)0 : G[(size_t)(r - 1) * G4 + d];
    }
}
__global__ void s_k(const float* __restrict__ e, const u16* __restrict__ mB,
                    u16* __restrict__ sB) {
    int i = blockIdx.x * 256 + threadIdx.x;
    if (i < BT * H2) sB[i] = f2us(sigm(e[i]) * tanhf(us2f(mB[i])));
}
__global__ void z_k(const float* __restrict__ cWh, const float* __restrict__ cWu,
                    const float* __restrict__ Wv, float* __restrict__ z) {
    int idx = blockIdx.x * 256 + threadIdx.x;
    if (idx >= BT * SS) return;
    int r = idx >> 5, s = idx & 31;
    int b = r >> 9;
    const float* ph = cWh + (size_t)r * MDU_;
    const float* pu = cWu + (size_t)(b * SS + s) * MDU_;
    float acc = 0.f;
    for (int j = 0; j < MDU_; ++j) acc += tanhf(ph[j] + pu[j]) * Wv[j];
    z[idx] = acc;
}
__global__ void zhat_k(const float* __restrict__ sW, const float* __restrict__ cWh,
                       const float* __restrict__ Wv, float* __restrict__ zhat) {
    int r = blockIdx.x * 256 + threadIdx.x;
    if (r >= BT) return;
    float acc = 0.f;
    const float* ps = sW + (size_t)r * MDU_;
    const float* ph = cWh + (size_t)r * MDU_;
    for (int j = 0; j < MDU_; ++j) acc += tanhf(ps[j] + ph[j]) * Wv[j];
    zhat[r] = acc;
}
__global__ __launch_bounds__(64)
void attn_mix_k(const float* __restrict__ z, const float* __restrict__ zhat,
                const u16* __restrict__ U, const u16* __restrict__ sB,
                u16* __restrict__ G) {
    int r = blockIdx.x;
    int lane = threadIdx.x;
    int b = r >> 9;
    __shared__ float alpha[SS];
    float zv = (lane < SS) ? z[(size_t)r * SS + lane] : -1e30f;
    float mx = zv;
    for (int o = 32; o > 0; o >>= 1) mx = fmaxf(mx, __shfl_xor(mx, o));
    float ez = (lane < SS) ? expf(zv - mx) : 0.f;
    float s1 = ez;
    for (int o = 32; o > 0; o >>= 1) s1 += __shfl_xor(s1, o);
    float zh = zhat[r];
    float mx2 = fmaxf(mx, zh);
    float denom = s1 * expf(mx - mx2) + expf(zh - mx2);
    float beta = expf(zh - mx2) / denom;
    if (lane < SS) alpha[lane] = ez / s1;
    __syncthreads();
    for (int d = lane; d < H2; d += 64) {
        float cv = 0.f;
#pragma unroll 8
        for (int s2 = 0; s2 < SS; ++s2)
            cv += alpha[s2] * us2f(U[(size_t)(b * SS + s2) * H2 + d]);
        float sv = us2f(sB[(size_t)r * H2 + d]);
        G[(size_t)r * G4 + H2 + d] = f2us(beta * sv + (1.f - beta) * cv);
    }
}
__global__ __launch_bounds__(256)
void logit_k(const u16* __restrict__ G, const u16* __restrict__ Mb,
             const u16* __restrict__ Wout, const float* __restrict__ boutF,
             void* __restrict__ out, const int* __restrict__ flag) {
    int r = blockIdx.x * 4 + (threadIdx.x >> 6);
    if (r >= BT) return;
    int lane = threadIdx.x & 63;
    float acc[TAGS_] = {0, 0, 0, 0, 0, 0, 0};
    for (int k = lane; k < 1536; k += 64) {
        float v = (k < G4) ? us2f(G[(size_t)r * G4 + k]) : us2f(Mb[(size_t)r * H2 + (k - G4)]);
#pragma unroll
        for (int tg = 0; tg < TAGS_; ++tg) acc[tg] += v * us2f(Wout[tg * 1536 + k]);
    }
#pragma unroll
    for (int tg = 0; tg < TAGS_; ++tg) {
        float s = acc[tg];
        for (int o = 32; o > 0; o >>= 1) s += __shfl_xor(s, o);
        acc[tg] = s;
    }
    if (lane == 0) {
        int bf = *flag;
#pragma unroll
        for (int tg = 0; tg < TAGS_; ++tg) {
            float v = acc[tg] + boutF[tg];
            if (bf) ((u16*)out)[(size_t)r * TAGS_ + tg] = f2us(v);
            else    ((float*)out)[(size_t)r * TAGS_ + tg] = v;
        }
    }
}

// ---------------------------------------------------------------------------
extern "C" void kernel_launch(void* const* d_in, const int* in_sizes, int n_in,
                              void* d_out, int out_size, void* d_ws, size_t ws_size,
                              hipStream_t stream)
{
    const void* x_text = d_in[0];
    const void* x_syn  = d_in[1];
    const int* len_ctx = (const int*)d_in[3];
    const void *Wih[6], *Whh[6], *bih[6], *bhh[6];
    for (int l = 0; l < 6; ++l) {
        Wih[l] = d_in[5 + l * 4 + 0];
        Whh[l] = d_in[5 + l * 4 + 1];
        bih[l] = d_in[5 + l * 4 + 2];
        bhh[l] = d_in[5 + l * 4 + 3];
    }
    const void* W_cWh = d_in[29];
    const void* W_cWu = d_in[30];
    const void* W_v   = d_in[31];
    const void* W_sWh = d_in[32];
    const void* W_sWu = d_in[33];
    const void* W_Ws  = d_in[34];
    const void* W_out = d_in[35];
    const void* b_out = d_in[36];
    (void)in_sizes; (void)n_in; (void)out_size; (void)ws_size;

    char* ws = (char*)d_ws;
    size_t off = 0;
    auto alloc = [&](size_t bytes) -> void* {
        void* p = ws + off;
        off += (bytes + 255) & ~(size_t)255;
        return p;
    };
    int*   flagB  = (int*)alloc(256);
    float* bsum[6];
    for (int l = 0; l < 6; ++l) bsum[l] = (float*)alloc((size_t)G4 * 4);
    u16*   WsumB  = (u16*)alloc((size_t)H2 * H2 * 2);
    u16*   Ub     = (u16*)alloc((size_t)NSEQ * H2 * 2);
    u16*   Gb     = (u16*)alloc((size_t)BT * G4 * 2);
    u16*   mMb    = (u16*)alloc((size_t)BT * H2 * 2);
    float* cWhB   = (float*)alloc((size_t)BT * MDU_ * 4);
    float* cWuB   = (float*)alloc((size_t)NSEQ * MDU_ * 4);
    float* sWB    = (float*)alloc((size_t)BT * MDU_ * 4);
    float* zB     = (float*)alloc((size_t)BT * SS * 4);
    float* zhatB  = (float*)alloc((size_t)BT * 4);
    u16*   Wout16 = (u16*)alloc((size_t)TAGS_ * 1536 * 2);
    float* WvF    = (float*)alloc((size_t)MDU_ * 4);
    float* boutF  = (float*)alloc((size_t)TAGS_ * 4);
    u16*   WF[6];
    for (int l = 0; l < 6; ++l) WF[l] = (u16*)alloc((size_t)G4 * RR * 2);   // 512KB each
    char*  BIG    = (char*)alloc((size_t)24 * MB1);

    u16*   bufA  = (u16*)BIG;                       // 8MB xW fwd
    u16*   bufB  = (u16*)(BIG + (size_t)8 * MB1);   // 8MB xW bwd
    u16*   HprevB = (u16*)BIG;                      // phase C overlays
    float* eBuf   = (float*)(BIG + (size_t)4 * MB1);
    u16*   sBuf   = (u16*)(BIG + (size_t)12 * MB1);
    u16*   mxWf  = (u16*)BIG;                       // phase D overlays
    u16*   mxWb  = (u16*)(BIG + (size_t)8 * MB1);

    auto cgrid = [](long n) { return dim3((unsigned)((n + 255) / 256)); };

    // ---- prep ----
    detect_k<<<dim3(1), dim3(256), 0, stream>>>(x_text, flagB);
    castbf_k<<<cgrid(TAGS_ * 1536), dim3(256), 0, stream>>>(W_out, 0, Wout16, TAGS_ * 1536, flagB);
    castf_k<<<cgrid(MDU_), dim3(256), 0, stream>>>(W_v, WvF, MDU_, flagB);
    castf_k<<<cgrid(TAGS_), dim3(256), 0, stream>>>(b_out, boutF, TAGS_, flagB);
    for (int l = 0; l < 6; ++l) {
        bias_sum_k<<<dim3(4), dim3(256), 0, stream>>>(bih[l], bhh[l], bsum[l], flagB);
        whh_frag_k<<<dim3(1024), dim3(256), 0, stream>>>(Whh[l], WF[l], flagB);
    }
    wsum_k<<<cgrid(H2 * H2), dim3(256), 0, stream>>>(W_sWh, W_sWu, WsumB, flagB);

    // ---- phase A: synopsis (4 chunks of 64 seqs) -> U ----
    for (int c = 0; c < NSEQ / SCH; ++c) {
        long aOff = (long)c * SCH * JJ * DD;
        gemm_bt<<<dim3(8, (SCH * JJ) / BM), dim3(256), 0, stream>>>(
            x_syn, aOff, DD, Wih[2], DD, bufA, G4, bsum[2], SCH * JJ, G4, DD, 1, 1, 1, flagB);
        gemm_bt<<<dim3(8, (SCH * JJ) / BM), dim3(256), 0, stream>>>(
            x_syn, aOff, DD, Wih[3], DD, bufB, G4, bsum[3], SCH * JJ, G4, DD, 1, 1, 1, flagB);
        lstm_solo<<<dim3(2, 8), dim3(1024), 0, stream>>>(
            bufA, bufB, WF[2], WF[3], JJ,
            Ub, H2, (u16*)nullptr, 0, (const int*)nullptr,
            0, 1, c * SCH);
    }

    // ---- phase B: context layer-1 -> H (Gb left), m (mMb) ----
    gemm_bt<<<dim3(8, 32), dim3(256), 0, stream>>>(
        x_text, 0, DD, Wih[0], DD, bufA, G4, bsum[0], BT, G4, DD, 1, 1, 1, flagB);
    gemm_bt<<<dim3(8, 32), dim3(256), 0, stream>>>(
        x_text, 0, DD, Wih[1], DD, bufB, G4, bsum[1], BT, G4, DD, 1, 1, 1, flagB);
    lstm_solo<<<dim3(2, 1), dim3(1024), 0, stream>>>(
        bufA, bufB, WF[0], WF[1], TT,
        Gb, G4, mMb, H2, len_ctx, 0, 0, 0);

    // ---- phase C: attention ----
    gemm_bt<<<dim3(1, 32), dim3(256), 0, stream>>>(
        Gb, 0, G4, W_cWh, H2, cWhB, MDU_, nullptr, BT, MDU_, H2, 0, 0, 1, flagB);
    gemm_bt<<<dim3(1, 2), dim3(256), 0, stream>>>(
        Ub, 0, H2, W_cWu, H2, cWuB, MDU_, nullptr, NSEQ, MDU_, H2, 0, 0, 1, flagB);
    hprev_k<<<cgrid(BT * H2), dim3(256), 0, stream>>>(Gb, HprevB);
    gemm_bt<<<dim3(4, 32), dim3(256), 0, stream>>>(
        HprevB, 0, H2, WsumB, H2, eBuf, H2, nullptr, BT, H2, H2, 0, 0, 0, nullptr);
    s_k<<<cgrid(BT * H2), dim3(256), 0, stream>>>(eBuf, mMb, sBuf);
    gemm_bt<<<dim3(1, 32), dim3(256), 0, stream>>>(
        sBuf, 0, H2, W_Ws, H2, sWB, MDU_, nullptr, BT, MDU_, H2, 0, 0, 1, flagB);
    z_k<<<cgrid(BT * SS), dim3(256), 0, stream>>>(cWhB, cWuB, WvF, zB);
    zhat_k<<<cgrid(BT), dim3(256), 0, stream>>>(sWB, cWhB, WvF, zhatB);
    attn_mix_k<<<dim3(BT), dim3(64), 0, stream>>>(zB, zhatB, Ub, sBuf, Gb);

    // ---- phase D: layer-2 LSTMs over G -> M (into mMb) ----
    gemm_bt<<<dim3(8, 32), dim3(256), 0, stream>>>(
        Gb, 0, G4, Wih[4], G4, mxWf, G4, bsum[4], BT, G4, G4, 1, 0, 1, flagB);
    gemm_bt<<<dim3(8, 32), dim3(256), 0, stream>>>(
        Gb, 0, G4, Wih[5], G4, mxWb, G4, bsum[5], BT, G4, G4, 1, 0, 1, flagB);
    lstm_solo<<<dim3(2, 1), dim3(1024), 0, stream>>>(
        mxWf, mxWb, WF[4], WF[5], TT,
        mMb, H2, (u16*)nullptr, 0, (const int*)nullptr, 1, 0, 0);

    // ---- output ----
    logit_k<<<dim3(BT / 4), dim3(256), 0, stream>>>(Gb, mMb, Wout16, boutF, d_out, flagB);
}